// Round 2
// baseline (695.810 us; speedup 1.0000x reference)
//
#include <hip/hip_runtime.h>
#include <hip/hip_bf16.h>
#include <stdint.h>

// ---------------------------------------------------------------------------
// GQA fused block: x->QKV proj (bf16 MFMA), RMSNorm+RoPE, causal GQA flash
// attention, O-proj. Round 1: resubmit of round-0 baseline (infra timeout).
// ---------------------------------------------------------------------------

#define B_  2
#define S_  2048
#define D_  2048
#define QH_ 32
#define KVH_ 8
#define HD_ 64

typedef unsigned short u16;
typedef __bf16  bf16x8 __attribute__((ext_vector_type(8)));
typedef float   f32x4  __attribute__((ext_vector_type(4)));
typedef u16     u16x8  __attribute__((ext_vector_type(8)));

__device__ __forceinline__ u16 f2b(float f) {
  unsigned u = __float_as_uint(f);
  u += 0x7fffu + ((u >> 16) & 1u);        // round-to-nearest-even
  return (u16)(u >> 16);
}

// async global -> LDS, 16B per lane. LDS dest = wave-uniform base + lane*16.
__device__ __forceinline__ void gload16(const void* g, void* l) {
  __builtin_amdgcn_global_load_lds(
      (const __attribute__((address_space(1))) void*)(uintptr_t)g,
      (__attribute__((address_space(3))) void*)(uint32_t)(uintptr_t)l,
      16, 0, 0);
}

// ---------------------------------------------------------------------------
__global__ __launch_bounds__(256) void cast_f32_bf16(
    const float* __restrict__ in, u16* __restrict__ out, int n4) {
  int i = blockIdx.x * 256 + threadIdx.x;
  if (i >= n4) return;
  float4 v = *reinterpret_cast<const float4*>(&in[(size_t)i * 4]);
  u16 o0 = f2b(v.x), o1 = f2b(v.y), o2 = f2b(v.z), o3 = f2b(v.w);
  unsigned lo = (unsigned)o0 | ((unsigned)o1 << 16);
  unsigned hi = (unsigned)o2 | ((unsigned)o3 << 16);
  uint2 pk; pk.x = lo; pk.y = hi;
  *reinterpret_cast<uint2*>(&out[(size_t)i * 4]) = pk;
}

// ---------------------------------------------------------------------------
// C(M,N) fp32 = A(M,K)bf16 . B(N,K)bf16^T ; tiles 128x128, BK=32, 4 waves.
__global__ __launch_bounds__(256) void gemm_bt(
    const u16* __restrict__ A, const u16* __restrict__ Bm,
    float* __restrict__ C, int M, int N, int K) {
  __shared__ u16 lA[128 * 32];
  __shared__ u16 lB[128 * 32];
  const int t = threadIdx.x, lane = t & 63, wid = t >> 6;
  const int m0 = blockIdx.y * 128, n0 = blockIdx.x * 128;
  const int wm = (wid >> 1) * 64, wn = (wid & 1) * 64;
  f32x4 acc[4][4] = {};
  const int srow = t >> 2, scol = (t & 3) * 8;     // 64B rows, 4 lanes/row
  const u16* gA = A + (size_t)(m0 + srow) * K + scol;
  const u16* gB = Bm + (size_t)(n0 + srow) * K + scol;

  for (int k0 = 0; k0 < K; k0 += 32) {
    gload16(gA + k0,                  &lA[wid * 512]);
    gload16(gA + k0 + (size_t)64 * K, &lA[2048 + wid * 512]);
    gload16(gB + k0,                  &lB[wid * 512]);
    gload16(gB + k0 + (size_t)64 * K, &lB[2048 + wid * 512]);
    __syncthreads();
    const int rb = lane & 15, ko = (lane >> 4) * 8;
    bf16x8 af[4], bfr[4];
#pragma unroll
    for (int i = 0; i < 4; i++)
      af[i] = *reinterpret_cast<const bf16x8*>(&lA[(wm + i * 16 + rb) * 32 + ko]);
#pragma unroll
    for (int i = 0; i < 4; i++)
      bfr[i] = *reinterpret_cast<const bf16x8*>(&lB[(wn + i * 16 + rb) * 32 + ko]);
#pragma unroll
    for (int i = 0; i < 4; i++)
#pragma unroll
      for (int j = 0; j < 4; j++)
        acc[i][j] = __builtin_amdgcn_mfma_f32_16x16x32_bf16(af[i], bfr[j], acc[i][j], 0, 0, 0);
    __syncthreads();
  }
  const int col = lane & 15, rg = (lane >> 4) * 4;
#pragma unroll
  for (int i = 0; i < 4; i++)
#pragma unroll
    for (int j = 0; j < 4; j++)
#pragma unroll
      for (int r = 0; r < 4; r++)
        C[(size_t)(m0 + wm + i * 16 + rg + r) * N + (n0 + wn + j * 16 + col)] = acc[i][j][r];
}

// ---------------------------------------------------------------------------
// RMSNorm(+RoPE) + transpose to (b,H,s,hd). mode 0: Q(bf16, pre-scaled)
// mode 1: K(bf16 + fp32 out) ; mode 2: V(copy, bf16 + fp32 out)
__global__ __launch_bounds__(256) void postproc(
    const float* __restrict__ lin, const float* __restrict__ freq,
    const float* __restrict__ nw, u16* __restrict__ outb,
    float* __restrict__ outf, int H, int mode, float oscale) {
  int p = blockIdx.x * 256 + threadIdx.x;   // pair index
  int i = p & 31;
  int h = (p >> 5) & (H - 1);
  int s = (p / (32 * H)) & (S_ - 1);
  int b = p / (32 * H * S_);
  float2 xv = *reinterpret_cast<const float2*>(
      &lin[(((size_t)b * S_ + s) * H + h) * 64 + 2 * i]);
  float x1 = xv.x, x2 = xv.y;
  if (mode < 2) {
    float ss = x1 * x1 + x2 * x2;
    ss += __shfl_xor(ss, 1);  ss += __shfl_xor(ss, 2);
    ss += __shfl_xor(ss, 4);  ss += __shfl_xor(ss, 8);
    ss += __shfl_xor(ss, 16);                        // 32-lane group = one row
    float inv = rsqrtf(ss * (1.0f / 64.0f) + 1e-6f);
    x1 *= inv * nw[2 * i];
    x2 *= inv * nw[2 * i + 1];
    float a = freq[(size_t)s * 32 + i];
    float sn, cs;
    __sincosf(a, &sn, &cs);
    float o1 = x1 * cs - x2 * sn;
    float o2 = x1 * sn + x2 * cs;
    x1 = o1; x2 = o2;
  }
  x1 *= oscale; x2 *= oscale;
  size_t oidx = (((size_t)b * H + h) * S_ + s) * 64 + 2 * i;
  unsigned pk = (unsigned)f2b(x1) | ((unsigned)f2b(x2) << 16);
  *reinterpret_cast<unsigned*>(&outb[oidx]) = pk;
  if (outf) {
    float2 o; o.x = x1; o.y = x2;
    *reinterpret_cast<float2*>(&outf[oidx]) = o;
  }
}

// ---------------------------------------------------------------------------
// Causal GQA flash attention. Block = (b,h,64 q-rows); 4 waves x 16 rows.
// KV tiles of 64. Q pre-scaled by 0.125. Ob: (b, s, QH*HD) bf16.
__global__ __launch_bounds__(256) void attn_fwd(
    const u16* __restrict__ Qb, const u16* __restrict__ Kb,
    const u16* __restrict__ Vb, u16* __restrict__ Ob) {
  __shared__ u16 lQ[64 * 64];
  __shared__ u16 lK[64 * 64];
  __shared__ u16 lVt[64 * 64];     // transposed: [hd][t_local]
  __shared__ u16 lP[4 * 16 * 64];  // per-wave P tile

  const int t = threadIdx.x, lane = t & 63, wid = t >> 6;
  const int blk = blockIdx.x;
  const int qt = blk & 31;
  const int h = (blk >> 5) & 31;
  const int b = blk >> 10;
  const int kvh = h >> 2;
  const int q0 = qt * 64;
  const size_t qbase = ((size_t)(b * QH_ + h) * S_ + q0) * 64;
  const size_t kbase = ((size_t)(b * KVH_ + kvh) * S_) * 64;

  {  // stage Q once (rows of 128B; 8 lanes/row)
    int row = t >> 3, cc = (t & 7) * 8;
    gload16(Qb + qbase + (size_t)row * 64 + cc,        &lQ[wid * 512]);
    gload16(Qb + qbase + (size_t)(32 + row) * 64 + cc, &lQ[2048 + wid * 512]);
  }

  f32x4 accO[4] = {};
  float M[4], L[4];
#pragma unroll
  for (int r = 0; r < 4; r++) { M[r] = -1e30f; L[r] = 0.0f; }

  const int nt = qt + 1;
  for (int tt = 0; tt < nt; ++tt) {
    const int t0 = tt * 64;
    {  // stage K tile
      int row = t >> 3, cc = (t & 7) * 8;
      gload16(Kb + kbase + (size_t)(t0 + row) * 64 + cc,      &lK[wid * 512]);
      gload16(Kb + kbase + (size_t)(t0 + 32 + row) * 64 + cc, &lK[2048 + wid * 512]);
    }
    {  // stage V transposed (scalar writes; optimize later)
      int sv = t >> 2, c0 = (t & 3) * 16;
      const u16* src = Vb + kbase + (size_t)(t0 + sv) * 64 + c0;
      u16x8 v0 = *reinterpret_cast<const u16x8*>(src);
      u16x8 v1 = *reinterpret_cast<const u16x8*>(src + 8);
#pragma unroll
      for (int j = 0; j < 8; j++) lVt[(c0 + j) * 64 + sv] = v0[j];
#pragma unroll
      for (int j = 0; j < 8; j++) lVt[(c0 + 8 + j) * 64 + sv] = v1[j];
    }
    __syncthreads();

    // S = Q.K^T for this wave's 16 rows x 64 cols
    const int rb = lane & 15, ko = (lane >> 4) * 8;
    bf16x8 aq0 = *reinterpret_cast<const bf16x8*>(&lQ[(wid * 16 + rb) * 64 + ko]);
    bf16x8 aq1 = *reinterpret_cast<const bf16x8*>(&lQ[(wid * 16 + rb) * 64 + 32 + ko]);
    f32x4 sc[4] = {};
#pragma unroll
    for (int nf = 0; nf < 4; nf++) {
      bf16x8 b0 = *reinterpret_cast<const bf16x8*>(&lK[(nf * 16 + rb) * 64 + ko]);
      bf16x8 b1 = *reinterpret_cast<const bf16x8*>(&lK[(nf * 16 + rb) * 64 + 32 + ko]);
      sc[nf] = __builtin_amdgcn_mfma_f32_16x16x32_bf16(aq0, b0, sc[nf], 0, 0, 0);
      sc[nf] = __builtin_amdgcn_mfma_f32_16x16x32_bf16(aq1, b1, sc[nf], 0, 0, 0);
    }
    if (tt == qt) {  // causal mask on diagonal tile
#pragma unroll
      for (int nf = 0; nf < 4; nf++) {
        int colg = t0 + nf * 16 + rb;
#pragma unroll
        for (int r = 0; r < 4; r++) {
          int rowg = q0 + wid * 16 + ((lane >> 4) << 2) + r;
          if (colg > rowg) sc[nf][r] = -1e30f;
        }
      }
    }
    // online softmax (row stats across 16 lanes of each group)
    float fac[4];
#pragma unroll
    for (int r = 0; r < 4; r++) {
      float mx = fmaxf(fmaxf(sc[0][r], sc[1][r]), fmaxf(sc[2][r], sc[3][r]));
      mx = fmaxf(mx, __shfl_xor(mx, 1));
      mx = fmaxf(mx, __shfl_xor(mx, 2));
      mx = fmaxf(mx, __shfl_xor(mx, 4));
      mx = fmaxf(mx, __shfl_xor(mx, 8));
      float mn = fmaxf(M[r], mx);
      fac[r] = __expf(M[r] - mn);
      M[r] = mn;
    }
    float rs[4] = {0.f, 0.f, 0.f, 0.f};
#pragma unroll
    for (int nf = 0; nf < 4; nf++)
#pragma unroll
      for (int r = 0; r < 4; r++) {
        float pv = __expf(sc[nf][r] - M[r]);
        sc[nf][r] = pv;
        rs[r] += pv;
      }
#pragma unroll
    for (int r = 0; r < 4; r++) {
      float s4 = rs[r];
      s4 += __shfl_xor(s4, 1); s4 += __shfl_xor(s4, 2);
      s4 += __shfl_xor(s4, 4); s4 += __shfl_xor(s4, 8);
      L[r] = L[r] * fac[r] + s4;
      accO[0][r] *= fac[r]; accO[1][r] *= fac[r];
      accO[2][r] *= fac[r]; accO[3][r] *= fac[r];
    }
    // P -> LDS (C-layout to A-layout repack)
#pragma unroll
    for (int nf = 0; nf < 4; nf++)
#pragma unroll
      for (int r = 0; r < 4; r++)
        lP[wid * 1024 + (((lane >> 4) << 2) + r) * 64 + nf * 16 + rb] = f2b(sc[nf][r]);
    // O += P.V
#pragma unroll
    for (int ks = 0; ks < 2; ks++) {
      bf16x8 ap = *reinterpret_cast<const bf16x8*>(&lP[wid * 1024 + rb * 64 + ks * 32 + ko]);
#pragma unroll
      for (int nf = 0; nf < 4; nf++) {
        bf16x8 bv = *reinterpret_cast<const bf16x8*>(&lVt[(nf * 16 + rb) * 64 + ks * 32 + ko]);
        accO[nf] = __builtin_amdgcn_mfma_f32_16x16x32_bf16(ap, bv, accO[nf], 0, 0, 0);
      }
    }
    __syncthreads();
  }
  // epilogue
  const int rb = lane & 15;
#pragma unroll
  for (int nf = 0; nf < 4; nf++)
#pragma unroll
    for (int r = 0; r < 4; r++) {
      int rowg = q0 + wid * 16 + ((lane >> 4) << 2) + r;
      float val = accO[nf][r] / L[r];
      Ob[((size_t)b * S_ + rowg) * (QH_ * HD_) + h * 64 + nf * 16 + rb] = f2b(val);
    }
}

// ---------------------------------------------------------------------------
extern "C" void kernel_launch(void* const* d_in, const int* in_sizes, int n_in,
                              void* d_out, int out_size, void* d_ws, size_t ws_size,
                              hipStream_t stream) {
  const float* x    = (const float*)d_in[0];
  const float* freq = (const float*)d_in[1];
  const float* wq   = (const float*)d_in[2];
  const float* wk   = (const float*)d_in[3];
  const float* wv   = (const float*)d_in[4];
  const float* wo   = (const float*)d_in[5];
  const float* qnw  = (const float*)d_in[6];
  const float* knw  = (const float*)d_in[7];
  float* out = (float*)d_out;

  char* ws = (char*)d_ws;                       // ~100 MB total
  u16*  xb   = (u16*)(ws);                      // 16777216 B
  u16*  wqb  = (u16*)(ws + 16777216);           //  8388608 B (reused for wob)
  u16*  wkb  = (u16*)(ws + 25165824);           //  2097152 B
  u16*  wvb  = (u16*)(ws + 27262976);           //  2097152 B
  float* qlin = (float*)(ws + 29360128);        // 33554432 B (reused for ob)
  float* klin = (float*)(ws + 62914560);        //  8388608 B
  float* vlin = (float*)(ws + 71303168);        //  8388608 B
  u16*  qb   = (u16*)(ws + 79691776);           // 16777216 B
  u16*  kb   = (u16*)(ws + 96468992);           //  4194304 B
  u16*  vb   = (u16*)(ws + 100663296);          //  4194304 B
  u16*  wob = wqb;            // wq-bf16 dead after Q-proj GEMM
  u16*  ob  = (u16*)qlin;     // q_lin dead after postproc Q

  // 1) casts
  cast_f32_bf16<<<8192, 256, 0, stream>>>(x, xb, 2097152);
  cast_f32_bf16<<<4096, 256, 0, stream>>>(wq, wqb, 1048576);
  cast_f32_bf16<<<1024, 256, 0, stream>>>(wk, wkb, 262144);
  cast_f32_bf16<<<1024, 256, 0, stream>>>(wv, wvb, 262144);
  // 2) projections
  dim3 gq(16, 32), gkv(4, 32);
  gemm_bt<<<gq, 256, 0, stream>>>(xb, wqb, qlin, 4096, 2048, 2048);
  gemm_bt<<<gkv, 256, 0, stream>>>(xb, wkb, klin, 4096, 512, 2048);
  gemm_bt<<<gkv, 256, 0, stream>>>(xb, wvb, vlin, 4096, 512, 2048);
  // 3) norm + rope + layout (Q pre-scaled by HD^-1/2)
  postproc<<<16384, 256, 0, stream>>>(qlin, freq, qnw, qb, nullptr, QH_, 0, 0.125f);
  postproc<<<4096, 256, 0, stream>>>(klin, freq, knw, kb, out + 8388608, KVH_, 1, 1.0f);
  postproc<<<4096, 256, 0, stream>>>(vlin, freq, knw, vb, out + 10485760, KVH_, 2, 1.0f);
  // wo cast into the dead wq slot
  cast_f32_bf16<<<4096, 256, 0, stream>>>(wo, wob, 1048576);
  // 4) attention
  attn_fwd<<<2048, 256, 0, stream>>>(qb, kb, vb, ob);
  // 5) output projection
  gemm_bt<<<gq, 256, 0, stream>>>(ob, wob, out, 4096, 2048, 2048);
}

// Round 6
// 513.558 us; speedup vs baseline: 1.3549x; 1.3549x over previous
//
#include <hip/hip_runtime.h>
#include <hip/hip_bf16.h>
#include <stdint.h>

// ---------------------------------------------------------------------------
// GQA fused block. Round 5 resubmit (three consecutive infra failures; kernel
// byte-identical to keep the pending A/B vs the 696 us baseline clean).
// attn rework: V pre-transposed, XOR-swizzled LDS (T2), paired-u32 P writes,
// 2-phase double-buffered KV prefetch, Q-frag hoist, tail-first launch order.
// ---------------------------------------------------------------------------

#define B_  2
#define S_  2048
#define D_  2048
#define QH_ 32
#define KVH_ 8
#define HD_ 64

typedef unsigned short u16;
typedef __bf16  bf16x8 __attribute__((ext_vector_type(8)));
typedef float   f32x4  __attribute__((ext_vector_type(4)));
typedef u16     u16x8  __attribute__((ext_vector_type(8)));

__device__ __forceinline__ u16 f2b(float f) {
  unsigned u = __float_as_uint(f);
  u += 0x7fffu + ((u >> 16) & 1u);        // round-to-nearest-even
  return (u16)(u >> 16);
}

// async global -> LDS, 16B per lane. LDS dest = wave-uniform base + lane*16.
__device__ __forceinline__ void gload16(const void* g, void* l) {
  __builtin_amdgcn_global_load_lds(
      (const __attribute__((address_space(1))) void*)(uintptr_t)g,
      (__attribute__((address_space(3))) void*)(uint32_t)(uintptr_t)l,
      16, 0, 0);
}

// swizzled LDS b128 read: logical (row, granule g of 8 u16) in a [*, 64] tile.
// Storage granule = g ^ (row & 7)  (matches pre-swizzled gload16 source).
#define LDS8(buf, row, g) \
  (*reinterpret_cast<const bf16x8*>(&(buf)[(row) * 64 + ((((g) ^ ((row) & 7))) << 3)]))

// ---------------------------------------------------------------------------
__global__ __launch_bounds__(256) void cast_f32_bf16(
    const float* __restrict__ in, u16* __restrict__ out, int n4) {
  int i = blockIdx.x * 256 + threadIdx.x;
  if (i >= n4) return;
  float4 v = *reinterpret_cast<const float4*>(&in[(size_t)i * 4]);
  u16 o0 = f2b(v.x), o1 = f2b(v.y), o2 = f2b(v.z), o3 = f2b(v.w);
  unsigned lo = (unsigned)o0 | ((unsigned)o1 << 16);
  unsigned hi = (unsigned)o2 | ((unsigned)o3 << 16);
  uint2 pk; pk.x = lo; pk.y = hi;
  *reinterpret_cast<uint2*>(&out[(size_t)i * 4]) = pk;
}

// ---------------------------------------------------------------------------
// C(M,N) fp32 = A(M,K)bf16 . B(N,K)bf16^T ; tiles 128x128, BK=32, 4 waves.
__global__ __launch_bounds__(256) void gemm_bt(
    const u16* __restrict__ A, const u16* __restrict__ Bm,
    float* __restrict__ C, int M, int N, int K) {
  __shared__ u16 lA[128 * 32];
  __shared__ u16 lB[128 * 32];
  const int t = threadIdx.x, lane = t & 63, wid = t >> 6;
  const int m0 = blockIdx.y * 128, n0 = blockIdx.x * 128;
  const int wm = (wid >> 1) * 64, wn = (wid & 1) * 64;
  f32x4 acc[4][4] = {};
  const int srow = t >> 2, scol = (t & 3) * 8;     // 64B rows, 4 lanes/row
  const u16* gA = A + (size_t)(m0 + srow) * K + scol;
  const u16* gB = Bm + (size_t)(n0 + srow) * K + scol;

  for (int k0 = 0; k0 < K; k0 += 32) {
    gload16(gA + k0,                  &lA[wid * 512]);
    gload16(gA + k0 + (size_t)64 * K, &lA[2048 + wid * 512]);
    gload16(gB + k0,                  &lB[wid * 512]);
    gload16(gB + k0 + (size_t)64 * K, &lB[2048 + wid * 512]);
    __syncthreads();
    const int rb = lane & 15, ko = (lane >> 4) * 8;
    bf16x8 af[4], bfr[4];
#pragma unroll
    for (int i = 0; i < 4; i++)
      af[i] = *reinterpret_cast<const bf16x8*>(&lA[(wm + i * 16 + rb) * 32 + ko]);
#pragma unroll
    for (int i = 0; i < 4; i++)
      bfr[i] = *reinterpret_cast<const bf16x8*>(&lB[(wn + i * 16 + rb) * 32 + ko]);
#pragma unroll
    for (int i = 0; i < 4; i++)
#pragma unroll
      for (int j = 0; j < 4; j++)
        acc[i][j] = __builtin_amdgcn_mfma_f32_16x16x32_bf16(af[i], bfr[j], acc[i][j], 0, 0, 0);
    __syncthreads();
  }
  const int col = lane & 15, rg = (lane >> 4) * 4;
#pragma unroll
  for (int i = 0; i < 4; i++)
#pragma unroll
    for (int j = 0; j < 4; j++)
#pragma unroll
      for (int r = 0; r < 4; r++)
        C[(size_t)(m0 + wm + i * 16 + rg + r) * N + (n0 + wn + j * 16 + col)] = acc[i][j][r];
}

// ---------------------------------------------------------------------------
// RMSNorm+RoPE + transpose to (b,H,s,hd). Q: bf16 pre-scaled; K: bf16+fp32.
__global__ __launch_bounds__(256) void postproc(
    const float* __restrict__ lin, const float* __restrict__ freq,
    const float* __restrict__ nw, u16* __restrict__ outb,
    float* __restrict__ outf, int H, float oscale) {
  int p = blockIdx.x * 256 + threadIdx.x;   // pair index
  int i = p & 31;
  int h = (p >> 5) & (H - 1);
  int s = (p / (32 * H)) & (S_ - 1);
  int b = p / (32 * H * S_);
  float2 xv = *reinterpret_cast<const float2*>(
      &lin[(((size_t)b * S_ + s) * H + h) * 64 + 2 * i]);
  float x1 = xv.x, x2 = xv.y;
  float ss = x1 * x1 + x2 * x2;
  ss += __shfl_xor(ss, 1);  ss += __shfl_xor(ss, 2);
  ss += __shfl_xor(ss, 4);  ss += __shfl_xor(ss, 8);
  ss += __shfl_xor(ss, 16);                        // 32-lane group = one row
  float inv = rsqrtf(ss * (1.0f / 64.0f) + 1e-6f);
  x1 *= inv * nw[2 * i];
  x2 *= inv * nw[2 * i + 1];
  float a = freq[(size_t)s * 32 + i];
  float sn, cs;
  __sincosf(a, &sn, &cs);
  float o1 = (x1 * cs - x2 * sn) * oscale;
  float o2 = (x1 * sn + x2 * cs) * oscale;
  size_t oidx = (((size_t)b * H + h) * S_ + s) * 64 + 2 * i;
  unsigned pk = (unsigned)f2b(o1) | ((unsigned)f2b(o2) << 16);
  *reinterpret_cast<unsigned*>(&outb[oidx]) = pk;
  if (outf) {
    float2 o; o.x = o1; o.y = o2;
    *reinterpret_cast<float2*>(&outf[oidx]) = o;
  }
}

// ---------------------------------------------------------------------------
// V: vlin (b,s,kvh,hd) f32 -> vnew (b,kvh,s,hd) f32  AND  vtb (b,kvh,hd,s) bf16
// One block = one (b,kvh, 64-s tile); LDS transpose.
__global__ __launch_bounds__(256) void v_trans(
    const float* __restrict__ vlin, float* __restrict__ vnew,
    u16* __restrict__ vtb) {
  __shared__ u16 tile[64 * 72];     // [hd][s_local], stride 72 u16 (16B-aligned rows)
  const int blk = blockIdx.x;
  const int st = blk & 31, kvh = (blk >> 5) & 7, b = blk >> 8;
  const int t = threadIdx.x;
  const int sl = t >> 2, c0 = (t & 3) * 16;
  const size_t src  = (((size_t)b * S_ + st * 64 + sl) * KVH_ + kvh) * 64 + c0;
  const size_t dstf = (((size_t)(b * KVH_ + kvh) * S_) + st * 64 + sl) * 64 + c0;
#pragma unroll
  for (int i = 0; i < 4; i++) {
    float4 f = *reinterpret_cast<const float4*>(&vlin[src + i * 4]);
    *reinterpret_cast<float4*>(&vnew[dstf + i * 4]) = f;
    tile[(c0 + i * 4 + 0) * 72 + sl] = f2b(f.x);
    tile[(c0 + i * 4 + 1) * 72 + sl] = f2b(f.y);
    tile[(c0 + i * 4 + 2) * 72 + sl] = f2b(f.z);
    tile[(c0 + i * 4 + 3) * 72 + sl] = f2b(f.w);
  }
  __syncthreads();
  const int hd = t >> 2, p0 = (t & 3) * 16;
  const size_t dstt = ((size_t)(b * KVH_ + kvh) * 64 + hd) * S_ + st * 64 + p0;
  uint4 lo = *reinterpret_cast<const uint4*>(&tile[hd * 72 + p0]);
  uint4 hi = *reinterpret_cast<const uint4*>(&tile[hd * 72 + p0 + 8]);
  *reinterpret_cast<uint4*>(&vtb[dstt])     = lo;
  *reinterpret_cast<uint4*>(&vtb[dstt + 8]) = hi;
}

// ---------------------------------------------------------------------------
// Causal GQA flash attention. Block = (b,h,64 q-rows); 4 waves x 16 rows.
// KV tiles of 64, double-buffered; V pre-transposed (b,kvh,hd,s).
// All LDS tiles XOR-swizzled at 16B granule: store g' = g ^ (row&7).
__global__ __launch_bounds__(256) void attn_fwd(
    const u16* __restrict__ Qb, const u16* __restrict__ Kb,
    const u16* __restrict__ Vt, u16* __restrict__ Ob) {
  __shared__ u16 lQ[4096];
  __shared__ u16 lK[2][4096];
  __shared__ u16 lV[2][4096];      // V^T tile: [hd][t_local]
  __shared__ u16 lP[4096];         // per-wave P tile [qrow][k], swizzled

  const int t = threadIdx.x, lane = t & 63, wid = t >> 6;
  const int blk = blockIdx.x;
  const int qt = 31 - (blk >> 6);          // longest blocks launch first
  const int bh = blk & 63;
  const int h = bh & 31;
  const int b = bh >> 5;
  const int kvh = h >> 2;
  const int q0 = qt * 64;
  const size_t qbase  = ((size_t)(b * QH_ + h) * S_ + q0) * 64;
  const size_t kbase  = ((size_t)(b * KVH_ + kvh) * S_) * 64;
  const size_t vtbase = ((size_t)(b * KVH_ + kvh) * 64) * S_;

  const int srow = t >> 3;                       // staging row 0..31
  const int sg8 = (((t & 7) ^ (srow & 7)) << 3); // pre-swizzled source granule*8

  {  // stage Q once
    gload16(Qb + qbase + (size_t)srow * 64 + sg8,        &lQ[wid * 512]);
    gload16(Qb + qbase + (size_t)(32 + srow) * 64 + sg8, &lQ[2048 + wid * 512]);
  }
#define STAGE_KV(kdst, vdst, t0)                                              \
  {                                                                           \
    gload16(Kb + kbase + (size_t)((t0) + srow) * 64 + sg8,      &(kdst)[wid * 512]); \
    gload16(Kb + kbase + (size_t)((t0) + 32 + srow) * 64 + sg8, &(kdst)[2048 + wid * 512]); \
    gload16(Vt + vtbase + (size_t)srow * S_ + (t0) + sg8,        &(vdst)[wid * 512]); \
    gload16(Vt + vtbase + (size_t)(32 + srow) * S_ + (t0) + sg8, &(vdst)[2048 + wid * 512]); \
  }
  STAGE_KV(lK[0], lV[0], 0)
  __syncthreads();

  const int rb = lane & 15, hi = lane >> 4;
  u16* lPw = &lP[wid * 1024];
  // hoisted Q fragments (rows wid*16+rb, k halves 0..31 / 32..63)
  const bf16x8 aq0 = LDS8(lQ, wid * 16 + rb, hi);
  const bf16x8 aq1 = LDS8(lQ, wid * 16 + rb, 4 + hi);

  f32x4 accO[4] = {};
  float M[4], L[4];
#pragma unroll
  for (int r = 0; r < 4; r++) { M[r] = -1e30f; L[r] = 0.0f; }

  const int nt = qt + 1;
  for (int tt = 0; tt < nt; ++tt) {
    const int cur = tt & 1;
    if (tt + 1 < nt) STAGE_KV(lK[cur ^ 1], lV[cur ^ 1], (tt + 1) * 64)
    const u16* lKc = lK[cur];
    const u16* lVc = lV[cur];

    // S = Q.K^T : 16 rows x 64 cols per wave
    f32x4 sc[4] = {};
#pragma unroll
    for (int nf = 0; nf < 4; nf++) {
      bf16x8 b0 = LDS8(lKc, nf * 16 + rb, hi);
      bf16x8 b1 = LDS8(lKc, nf * 16 + rb, 4 + hi);
      sc[nf] = __builtin_amdgcn_mfma_f32_16x16x32_bf16(aq0, b0, sc[nf], 0, 0, 0);
      sc[nf] = __builtin_amdgcn_mfma_f32_16x16x32_bf16(aq1, b1, sc[nf], 0, 0, 0);
    }
    if (tt == qt) {  // causal mask on diagonal tile
      const int t0 = tt * 64;
#pragma unroll
      for (int nf = 0; nf < 4; nf++) {
        int colg = t0 + nf * 16 + rb;
#pragma unroll
        for (int r = 0; r < 4; r++) {
          int rowg = q0 + wid * 16 + hi * 4 + r;
          if (colg > rowg) sc[nf][r] = -1e30f;
        }
      }
    }
    // online softmax (row stats across 16 lanes of each group)
    float fac[4];
#pragma unroll
    for (int r = 0; r < 4; r++) {
      float mx = fmaxf(fmaxf(sc[0][r], sc[1][r]), fmaxf(sc[2][r], sc[3][r]));
      mx = fmaxf(mx, __shfl_xor(mx, 1));
      mx = fmaxf(mx, __shfl_xor(mx, 2));
      mx = fmaxf(mx, __shfl_xor(mx, 4));
      mx = fmaxf(mx, __shfl_xor(mx, 8));
      float mn = fmaxf(M[r], mx);
      fac[r] = __expf(M[r] - mn);
      M[r] = mn;
    }
    float rs[4] = {0.f, 0.f, 0.f, 0.f};
#pragma unroll
    for (int nf = 0; nf < 4; nf++)
#pragma unroll
      for (int r = 0; r < 4; r++) {
        float pv = __expf(sc[nf][r] - M[r]);
        sc[nf][r] = pv;
        rs[r] += pv;
      }
#pragma unroll
    for (int r = 0; r < 4; r++) {
      float s4 = rs[r];
      s4 += __shfl_xor(s4, 1); s4 += __shfl_xor(s4, 2);
      s4 += __shfl_xor(s4, 4); s4 += __shfl_xor(s4, 8);
      L[r] = L[r] * fac[r] + s4;
      accO[0][r] *= fac[r]; accO[1][r] *= fac[r];
      accO[2][r] *= fac[r]; accO[3][r] *= fac[r];
    }
    // P -> LDS: pack col pairs via shfl, u32 stores, swizzled granule
#pragma unroll
    for (int nf = 0; nf < 4; nf++)
#pragma unroll
      for (int r = 0; r < 4; r++) {
        float own = sc[nf][r];
        float oth = __shfl_xor(own, 1);
        if (!(lane & 1)) {
          int row = hi * 4 + r;
          int col = nf * 16 + rb;          // even
          unsigned pk = (unsigned)f2b(own) | ((unsigned)f2b(oth) << 16);
          *reinterpret_cast<unsigned*>(&lPw[row * 64 + (col ^ ((row & 7) << 3))]) = pk;
        }
      }
    // O += P.V   (A = P rows, B = V^T rows = hd)
#pragma unroll
    for (int ks = 0; ks < 2; ks++) {
      bf16x8 ap = LDS8(lPw, rb, ks * 4 + hi);
#pragma unroll
      for (int nf = 0; nf < 4; nf++) {
        bf16x8 bv = LDS8(lVc, nf * 16 + rb, ks * 4 + hi);
        accO[nf] = __builtin_amdgcn_mfma_f32_16x16x32_bf16(ap, bv, accO[nf], 0, 0, 0);
      }
    }
    __syncthreads();
  }
  // epilogue: paired u32 stores
  float inv[4];
#pragma unroll
  for (int r = 0; r < 4; r++) inv[r] = 1.0f / L[r];
#pragma unroll
  for (int nf = 0; nf < 4; nf++)
#pragma unroll
    for (int r = 0; r < 4; r++) {
      float own = accO[nf][r] * inv[r];
      float oth = __shfl_xor(own, 1);
      if (!(lane & 1)) {
        int rowg = q0 + wid * 16 + hi * 4 + r;
        size_t idx = ((size_t)b * S_ + rowg) * (QH_ * HD_) + h * 64 + nf * 16 + rb;
        unsigned pk = (unsigned)f2b(own) | ((unsigned)f2b(oth) << 16);
        *reinterpret_cast<unsigned*>(&Ob[idx]) = pk;
      }
    }
}

// ---------------------------------------------------------------------------
extern "C" void kernel_launch(void* const* d_in, const int* in_sizes, int n_in,
                              void* d_out, int out_size, void* d_ws, size_t ws_size,
                              hipStream_t stream) {
  const float* x    = (const float*)d_in[0];
  const float* freq = (const float*)d_in[1];
  const float* wq   = (const float*)d_in[2];
  const float* wk   = (const float*)d_in[3];
  const float* wv   = (const float*)d_in[4];
  const float* wo   = (const float*)d_in[5];
  const float* qnw  = (const float*)d_in[6];
  const float* knw  = (const float*)d_in[7];
  float* out = (float*)d_out;

  char* ws = (char*)d_ws;                       // ~100 MB total
  u16*  xb   = (u16*)(ws);                      // 16777216 B
  u16*  wqb  = (u16*)(ws + 16777216);           //  8388608 B (reused for wob)
  u16*  wkb  = (u16*)(ws + 25165824);           //  2097152 B
  u16*  wvb  = (u16*)(ws + 27262976);           //  2097152 B
  float* qlin = (float*)(ws + 29360128);        // 33554432 B (reused for ob)
  float* klin = (float*)(ws + 62914560);        //  8388608 B
  float* vlin = (float*)(ws + 71303168);        //  8388608 B
  u16*  qb   = (u16*)(ws + 79691776);           // 16777216 B
  u16*  kb   = (u16*)(ws + 96468992);           //  4194304 B
  u16*  vtb  = (u16*)(ws + 100663296);          //  4194304 B (V^T bf16)
  u16*  wob = wqb;            // wq-bf16 dead after Q-proj GEMM
  u16*  ob  = (u16*)qlin;     // q_lin dead after postproc Q

  // 1) casts
  cast_f32_bf16<<<8192, 256, 0, stream>>>(x, xb, 2097152);
  cast_f32_bf16<<<4096, 256, 0, stream>>>(wq, wqb, 1048576);
  cast_f32_bf16<<<1024, 256, 0, stream>>>(wk, wkb, 262144);
  cast_f32_bf16<<<1024, 256, 0, stream>>>(wv, wvb, 262144);
  // 2) projections
  dim3 gq(16, 32), gkv(4, 32);
  gemm_bt<<<gq, 256, 0, stream>>>(xb, wqb, qlin, 4096, 2048, 2048);
  gemm_bt<<<gkv, 256, 0, stream>>>(xb, wkb, klin, 4096, 512, 2048);
  gemm_bt<<<gkv, 256, 0, stream>>>(xb, wvb, vlin, 4096, 512, 2048);
  // 3) norm + rope + layout (Q pre-scaled by HD^-1/2); V transpose
  postproc<<<16384, 256, 0, stream>>>(qlin, freq, qnw, qb, nullptr, QH_, 0.125f);
  postproc<<<4096, 256, 0, stream>>>(klin, freq, knw, kb, out + 8388608, KVH_, 1.0f);
  v_trans<<<512, 256, 0, stream>>>(vlin, out + 10485760, vtb);
  // wo cast into the dead wq slot
  cast_f32_bf16<<<4096, 256, 0, stream>>>(wo, wob, 1048576);
  // 4) attention
  attn_fwd<<<2048, 256, 0, stream>>>(qb, kb, vtb, ob);
  // 5) output projection
  gemm_bt<<<gq, 256, 0, stream>>>(ob, wob, out, 4096, 2048, 2048);
}

// Round 10
// 498.281 us; speedup vs baseline: 1.3964x; 1.0307x over previous
//
#include <hip/hip_runtime.h>
#include <hip/hip_bf16.h>
#include <stdint.h>

// ---------------------------------------------------------------------------
// GQA fused block. Round 10: fourth submit of the round-7 diff (three infra
// timeouts; byte-identical to keep the A/B vs 513.6 us clean).
// Round-7 diff: attn occupancy fix (lP aliased onto dead lQ, 48->40KB LDS ->
// 4 blocks/CU), exp2-based softmax (log2e folded into Q pre-scale),
// XCD-chunked block swizzle on GEMMs (T1).
// ---------------------------------------------------------------------------

#define B_  2
#define S_  2048
#define D_  2048
#define QH_ 32
#define KVH_ 8
#define HD_ 64

typedef unsigned short u16;
typedef __bf16  bf16x8 __attribute__((ext_vector_type(8)));
typedef float   f32x4  __attribute__((ext_vector_type(4)));
typedef u16     u16x8  __attribute__((ext_vector_type(8)));

__device__ __forceinline__ u16 f2b(float f) {
  unsigned u = __float_as_uint(f);
  u += 0x7fffu + ((u >> 16) & 1u);        // round-to-nearest-even
  return (u16)(u >> 16);
}

// async global -> LDS, 16B per lane. LDS dest = wave-uniform base + lane*16.
__device__ __forceinline__ void gload16(const void* g, void* l) {
  __builtin_amdgcn_global_load_lds(
      (const __attribute__((address_space(1))) void*)(uintptr_t)g,
      (__attribute__((address_space(3))) void*)(uint32_t)(uintptr_t)l,
      16, 0, 0);
}

// swizzled LDS b128 read: logical (row, granule g of 8 u16) in a [*, 64] tile.
// Storage granule = g ^ (row & 7)  (matches pre-swizzled gload16 source).
#define LDS8(buf, row, g) \
  (*reinterpret_cast<const bf16x8*>(&(buf)[(row) * 64 + ((((g) ^ ((row) & 7))) << 3)]))

// ---------------------------------------------------------------------------
__global__ __launch_bounds__(256) void cast_f32_bf16(
    const float* __restrict__ in, u16* __restrict__ out, int n4) {
  int i = blockIdx.x * 256 + threadIdx.x;
  if (i >= n4) return;
  float4 v = *reinterpret_cast<const float4*>(&in[(size_t)i * 4]);
  u16 o0 = f2b(v.x), o1 = f2b(v.y), o2 = f2b(v.z), o3 = f2b(v.w);
  unsigned lo = (unsigned)o0 | ((unsigned)o1 << 16);
  unsigned hi = (unsigned)o2 | ((unsigned)o3 << 16);
  uint2 pk; pk.x = lo; pk.y = hi;
  *reinterpret_cast<uint2*>(&out[(size_t)i * 4]) = pk;
}

// ---------------------------------------------------------------------------
// C(M,N) fp32 = A(M,K)bf16 . B(N,K)bf16^T ; tiles 128x128, BK=32, 4 waves.
// XCD-chunked block swizzle (bijective; grid size always divisible by 8).
__global__ __launch_bounds__(256) void gemm_bt(
    const u16* __restrict__ A, const u16* __restrict__ Bm,
    float* __restrict__ C, int M, int N, int K) {
  __shared__ u16 lA[128 * 32];
  __shared__ u16 lB[128 * 32];
  const int t = threadIdx.x, lane = t & 63, wid = t >> 6;
  const int nwg = gridDim.x * gridDim.y;
  const int flat = blockIdx.y * gridDim.x + blockIdx.x;
  const int swz = (flat & 7) * (nwg >> 3) + (flat >> 3);
  const int m0 = (swz / gridDim.x) * 128, n0 = (swz % gridDim.x) * 128;
  const int wm = (wid >> 1) * 64, wn = (wid & 1) * 64;
  f32x4 acc[4][4] = {};
  const int srow = t >> 2, scol = (t & 3) * 8;     // 64B rows, 4 lanes/row
  const u16* gA = A + (size_t)(m0 + srow) * K + scol;
  const u16* gB = Bm + (size_t)(n0 + srow) * K + scol;

  for (int k0 = 0; k0 < K; k0 += 32) {
    gload16(gA + k0,                  &lA[wid * 512]);
    gload16(gA + k0 + (size_t)64 * K, &lA[2048 + wid * 512]);
    gload16(gB + k0,                  &lB[wid * 512]);
    gload16(gB + k0 + (size_t)64 * K, &lB[2048 + wid * 512]);
    __syncthreads();
    const int rb = lane & 15, ko = (lane >> 4) * 8;
    bf16x8 af[4], bfr[4];
#pragma unroll
    for (int i = 0; i < 4; i++)
      af[i] = *reinterpret_cast<const bf16x8*>(&lA[(wm + i * 16 + rb) * 32 + ko]);
#pragma unroll
    for (int i = 0; i < 4; i++)
      bfr[i] = *reinterpret_cast<const bf16x8*>(&lB[(wn + i * 16 + rb) * 32 + ko]);
#pragma unroll
    for (int i = 0; i < 4; i++)
#pragma unroll
      for (int j = 0; j < 4; j++)
        acc[i][j] = __builtin_amdgcn_mfma_f32_16x16x32_bf16(af[i], bfr[j], acc[i][j], 0, 0, 0);
    __syncthreads();
  }
  const int col = lane & 15, rg = (lane >> 4) * 4;
#pragma unroll
  for (int i = 0; i < 4; i++)
#pragma unroll
    for (int j = 0; j < 4; j++)
#pragma unroll
      for (int r = 0; r < 4; r++)
        C[(size_t)(m0 + wm + i * 16 + rg + r) * N + (n0 + wn + j * 16 + col)] = acc[i][j][r];
}

// ---------------------------------------------------------------------------
// RMSNorm+RoPE + transpose to (b,H,s,hd). Q: bf16 pre-scaled; K: bf16+fp32.
__global__ __launch_bounds__(256) void postproc(
    const float* __restrict__ lin, const float* __restrict__ freq,
    const float* __restrict__ nw, u16* __restrict__ outb,
    float* __restrict__ outf, int H, float oscale) {
  int p = blockIdx.x * 256 + threadIdx.x;   // pair index
  int i = p & 31;
  int h = (p >> 5) & (H - 1);
  int s = (p / (32 * H)) & (S_ - 1);
  int b = p / (32 * H * S_);
  float2 xv = *reinterpret_cast<const float2*>(
      &lin[(((size_t)b * S_ + s) * H + h) * 64 + 2 * i]);
  float x1 = xv.x, x2 = xv.y;
  float ss = x1 * x1 + x2 * x2;
  ss += __shfl_xor(ss, 1);  ss += __shfl_xor(ss, 2);
  ss += __shfl_xor(ss, 4);  ss += __shfl_xor(ss, 8);
  ss += __shfl_xor(ss, 16);                        // 32-lane group = one row
  float inv = rsqrtf(ss * (1.0f / 64.0f) + 1e-6f);
  x1 *= inv * nw[2 * i];
  x2 *= inv * nw[2 * i + 1];
  float a = freq[(size_t)s * 32 + i];
  float sn, cs;
  __sincosf(a, &sn, &cs);
  float o1 = (x1 * cs - x2 * sn) * oscale;
  float o2 = (x1 * sn + x2 * cs) * oscale;
  size_t oidx = (((size_t)b * H + h) * S_ + s) * 64 + 2 * i;
  unsigned pk = (unsigned)f2b(o1) | ((unsigned)f2b(o2) << 16);
  *reinterpret_cast<unsigned*>(&outb[oidx]) = pk;
  if (outf) {
    float2 o; o.x = o1; o.y = o2;
    *reinterpret_cast<float2*>(&outf[oidx]) = o;
  }
}

// ---------------------------------------------------------------------------
// V: vlin (b,s,kvh,hd) f32 -> vnew (b,kvh,s,hd) f32  AND  vtb (b,kvh,hd,s) bf16
// One block = one (b,kvh, 64-s tile); LDS transpose.
__global__ __launch_bounds__(256) void v_trans(
    const float* __restrict__ vlin, float* __restrict__ vnew,
    u16* __restrict__ vtb) {
  __shared__ u16 tile[64 * 72];     // [hd][s_local], stride 72 u16 (16B-aligned rows)
  const int blk = blockIdx.x;
  const int st = blk & 31, kvh = (blk >> 5) & 7, b = blk >> 8;
  const int t = threadIdx.x;
  const int sl = t >> 2, c0 = (t & 3) * 16;
  const size_t src  = (((size_t)b * S_ + st * 64 + sl) * KVH_ + kvh) * 64 + c0;
  const size_t dstf = (((size_t)(b * KVH_ + kvh) * S_) + st * 64 + sl) * 64 + c0;
#pragma unroll
  for (int i = 0; i < 4; i++) {
    float4 f = *reinterpret_cast<const float4*>(&vlin[src + i * 4]);
    *reinterpret_cast<float4*>(&vnew[dstf + i * 4]) = f;
    tile[(c0 + i * 4 + 0) * 72 + sl] = f2b(f.x);
    tile[(c0 + i * 4 + 1) * 72 + sl] = f2b(f.y);
    tile[(c0 + i * 4 + 2) * 72 + sl] = f2b(f.z);
    tile[(c0 + i * 4 + 3) * 72 + sl] = f2b(f.w);
  }
  __syncthreads();
  const int hd = t >> 2, p0 = (t & 3) * 16;
  const size_t dstt = ((size_t)(b * KVH_ + kvh) * 64 + hd) * S_ + st * 64 + p0;
  uint4 lo = *reinterpret_cast<const uint4*>(&tile[hd * 72 + p0]);
  uint4 hi = *reinterpret_cast<const uint4*>(&tile[hd * 72 + p0 + 8]);
  *reinterpret_cast<uint4*>(&vtb[dstt])     = lo;
  *reinterpret_cast<uint4*>(&vtb[dstt + 8]) = hi;
}

// ---------------------------------------------------------------------------
// Causal GQA flash attention. Block = (b,h,64 q-rows); 4 waves x 16 rows.
// KV tiles of 64, double-buffered; V pre-transposed (b,kvh,hd,s).
// LDS tiles XOR-swizzled at 16B granule. P tile aliased onto dead lQ
// (aq0/aq1 hoisted to VGPRs) -> 40KB LDS -> 4 blocks/CU.
// Softmax in base-2: Q pre-scaled by 0.125*log2(e), exp2f throughout.
__global__ __launch_bounds__(256, 4) void attn_fwd(
    const u16* __restrict__ Qb, const u16* __restrict__ Kb,
    const u16* __restrict__ Vt, u16* __restrict__ Ob) {
  __shared__ u16 lQ[4096];         // Q rows; dead after frag hoist -> reused as P
  __shared__ u16 lK[2][4096];
  __shared__ u16 lV[2][4096];      // V^T tile: [hd][t_local]

  const int t = threadIdx.x, lane = t & 63, wid = t >> 6;
  const int blk = blockIdx.x;
  const int qt = 31 - (blk >> 6);          // longest blocks launch first
  const int bh = blk & 63;
  const int h = bh & 31;
  const int b = bh >> 5;
  const int kvh = h >> 2;
  const int q0 = qt * 64;
  const size_t qbase  = ((size_t)(b * QH_ + h) * S_ + q0) * 64;
  const size_t kbase  = ((size_t)(b * KVH_ + kvh) * S_) * 64;
  const size_t vtbase = ((size_t)(b * KVH_ + kvh) * 64) * S_;

  const int srow = t >> 3;                       // staging row 0..31
  const int sg8 = (((t & 7) ^ (srow & 7)) << 3); // pre-swizzled source granule*8

  {  // stage Q once
    gload16(Qb + qbase + (size_t)srow * 64 + sg8,        &lQ[wid * 512]);
    gload16(Qb + qbase + (size_t)(32 + srow) * 64 + sg8, &lQ[2048 + wid * 512]);
  }
#define STAGE_KV(kdst, vdst, t0)                                              \
  {                                                                           \
    gload16(Kb + kbase + (size_t)((t0) + srow) * 64 + sg8,      &(kdst)[wid * 512]); \
    gload16(Kb + kbase + (size_t)((t0) + 32 + srow) * 64 + sg8, &(kdst)[2048 + wid * 512]); \
    gload16(Vt + vtbase + (size_t)srow * S_ + (t0) + sg8,        &(vdst)[wid * 512]); \
    gload16(Vt + vtbase + (size_t)(32 + srow) * S_ + (t0) + sg8, &(vdst)[2048 + wid * 512]); \
  }
  STAGE_KV(lK[0], lV[0], 0)
  __syncthreads();

  const int rb = lane & 15, hi = lane >> 4;
  // hoisted Q fragments (rows wid*16+rb, k halves 0..31 / 32..63); after the
  // first-use waitcnt these live in VGPRs and lQ's chunk is dead -> P tile.
  const bf16x8 aq0 = LDS8(lQ, wid * 16 + rb, hi);
  const bf16x8 aq1 = LDS8(lQ, wid * 16 + rb, 4 + hi);
  u16* lPw = &lQ[wid * 1024];      // per-wave P tile aliases own Q rows

  f32x4 accO[4] = {};
  float M[4], L[4];
#pragma unroll
  for (int r = 0; r < 4; r++) { M[r] = -1e30f; L[r] = 0.0f; }

  const int nt = qt + 1;
  for (int tt = 0; tt < nt; ++tt) {
    const int cur = tt & 1;
    if (tt + 1 < nt) STAGE_KV(lK[cur ^ 1], lV[cur ^ 1], (tt + 1) * 64)
    const u16* lKc = lK[cur];
    const u16* lVc = lV[cur];

    // S = Q.K^T : 16 rows x 64 cols per wave (S already in log2 units)
    f32x4 sc[4] = {};
#pragma unroll
    for (int nf = 0; nf < 4; nf++) {
      bf16x8 b0 = LDS8(lKc, nf * 16 + rb, hi);
      bf16x8 b1 = LDS8(lKc, nf * 16 + rb, 4 + hi);
      sc[nf] = __builtin_amdgcn_mfma_f32_16x16x32_bf16(aq0, b0, sc[nf], 0, 0, 0);
      sc[nf] = __builtin_amdgcn_mfma_f32_16x16x32_bf16(aq1, b1, sc[nf], 0, 0, 0);
    }
    if (tt == qt) {  // causal mask on diagonal tile
      const int t0 = tt * 64;
#pragma unroll
      for (int nf = 0; nf < 4; nf++) {
        int colg = t0 + nf * 16 + rb;
#pragma unroll
        for (int r = 0; r < 4; r++) {
          int rowg = q0 + wid * 16 + hi * 4 + r;
          if (colg > rowg) sc[nf][r] = -1e30f;
        }
      }
    }
    // online softmax (base-2; row stats across 16 lanes of each group)
    float fac[4];
#pragma unroll
    for (int r = 0; r < 4; r++) {
      float mx = fmaxf(fmaxf(sc[0][r], sc[1][r]), fmaxf(sc[2][r], sc[3][r]));
      mx = fmaxf(mx, __shfl_xor(mx, 1));
      mx = fmaxf(mx, __shfl_xor(mx, 2));
      mx = fmaxf(mx, __shfl_xor(mx, 4));
      mx = fmaxf(mx, __shfl_xor(mx, 8));
      float mn = fmaxf(M[r], mx);
      fac[r] = exp2f(M[r] - mn);
      M[r] = mn;
    }
    float rs[4] = {0.f, 0.f, 0.f, 0.f};
#pragma unroll
    for (int nf = 0; nf < 4; nf++)
#pragma unroll
      for (int r = 0; r < 4; r++) {
        float pv = exp2f(sc[nf][r] - M[r]);
        sc[nf][r] = pv;
        rs[r] += pv;
      }
#pragma unroll
    for (int r = 0; r < 4; r++) {
      float s4 = rs[r];
      s4 += __shfl_xor(s4, 1); s4 += __shfl_xor(s4, 2);
      s4 += __shfl_xor(s4, 4); s4 += __shfl_xor(s4, 8);
      L[r] = L[r] * fac[r] + s4;
      accO[0][r] *= fac[r]; accO[1][r] *= fac[r];
      accO[2][r] *= fac[r]; accO[3][r] *= fac[r];
    }
    // P -> LDS: pack col pairs via shfl, u32 stores, swizzled granule
#pragma unroll
    for (int nf = 0; nf < 4; nf++)
#pragma unroll
      for (int r = 0; r < 4; r++) {
        float own = sc[nf][r];
        float oth = __shfl_xor(own, 1);
        if (!(lane & 1)) {
          int row = hi * 4 + r;
          int col = nf * 16 + rb;          // even
          unsigned pk = (unsigned)f2b(own) | ((unsigned)f2b(oth) << 16);
          *reinterpret_cast<unsigned*>(&lPw[row * 64 + (col ^ ((row & 7) << 3))]) = pk;
        }
      }
    // O += P.V   (A = P rows, B = V^T rows = hd)
#pragma unroll
    for (int ks = 0; ks < 2; ks++) {
      bf16x8 ap = LDS8(lPw, rb, ks * 4 + hi);
#pragma unroll
      for (int nf = 0; nf < 4; nf++) {
        bf16x8 bv = LDS8(lVc, nf * 16 + rb, ks * 4 + hi);
        accO[nf] = __builtin_amdgcn_mfma_f32_16x16x32_bf16(ap, bv, accO[nf], 0, 0, 0);
      }
    }
    __syncthreads();
  }
  // epilogue: paired u32 stores
  float inv[4];
#pragma unroll
  for (int r = 0; r < 4; r++) inv[r] = 1.0f / L[r];
#pragma unroll
  for (int nf = 0; nf < 4; nf++)
#pragma unroll
    for (int r = 0; r < 4; r++) {
      float own = accO[nf][r] * inv[r];
      float oth = __shfl_xor(own, 1);
      if (!(lane & 1)) {
        int rowg = q0 + wid * 16 + hi * 4 + r;
        size_t idx = ((size_t)b * S_ + rowg) * (QH_ * HD_) + h * 64 + nf * 16 + rb;
        unsigned pk = (unsigned)f2b(own) | ((unsigned)f2b(oth) << 16);
        *reinterpret_cast<unsigned*>(&Ob[idx]) = pk;
      }
    }
}

// ---------------------------------------------------------------------------
extern "C" void kernel_launch(void* const* d_in, const int* in_sizes, int n_in,
                              void* d_out, int out_size, void* d_ws, size_t ws_size,
                              hipStream_t stream) {
  const float* x    = (const float*)d_in[0];
  const float* freq = (const float*)d_in[1];
  const float* wq   = (const float*)d_in[2];
  const float* wk   = (const float*)d_in[3];
  const float* wv   = (const float*)d_in[4];
  const float* wo   = (const float*)d_in[5];
  const float* qnw  = (const float*)d_in[6];
  const float* knw  = (const float*)d_in[7];
  float* out = (float*)d_out;

  char* ws = (char*)d_ws;                       // ~100 MB total
  u16*  xb   = (u16*)(ws);                      // 16777216 B
  u16*  wqb  = (u16*)(ws + 16777216);           //  8388608 B (reused for wob)
  u16*  wkb  = (u16*)(ws + 25165824);           //  2097152 B
  u16*  wvb  = (u16*)(ws + 27262976);           //  2097152 B
  float* qlin = (float*)(ws + 29360128);        // 33554432 B (reused for ob)
  float* klin = (float*)(ws + 62914560);        //  8388608 B
  float* vlin = (float*)(ws + 71303168);        //  8388608 B
  u16*  qb   = (u16*)(ws + 79691776);           // 16777216 B
  u16*  kb   = (u16*)(ws + 96468992);           //  4194304 B
  u16*  vtb  = (u16*)(ws + 100663296);          //  4194304 B (V^T bf16)
  u16*  wob = wqb;            // wq-bf16 dead after Q-proj GEMM
  u16*  ob  = (u16*)qlin;     // q_lin dead after postproc Q

  // 1) casts
  cast_f32_bf16<<<8192, 256, 0, stream>>>(x, xb, 2097152);
  cast_f32_bf16<<<4096, 256, 0, stream>>>(wq, wqb, 1048576);
  cast_f32_bf16<<<1024, 256, 0, stream>>>(wk, wkb, 262144);
  cast_f32_bf16<<<1024, 256, 0, stream>>>(wv, wvb, 262144);
  // 2) projections
  dim3 gq(16, 32), gkv(4, 32);
  gemm_bt<<<gq, 256, 0, stream>>>(xb, wqb, qlin, 4096, 2048, 2048);
  gemm_bt<<<gkv, 256, 0, stream>>>(xb, wkb, klin, 4096, 512, 2048);
  gemm_bt<<<gkv, 256, 0, stream>>>(xb, wvb, vlin, 4096, 512, 2048);
  // 3) norm + rope + layout; Q pre-scaled by HD^-1/2 * log2(e) for exp2 softmax
  postproc<<<16384, 256, 0, stream>>>(qlin, freq, qnw, qb, nullptr, QH_, 0.18033688011112042f);
  postproc<<<4096, 256, 0, stream>>>(klin, freq, knw, kb, out + 8388608, KVH_, 1.0f);
  v_trans<<<512, 256, 0, stream>>>(vlin, out + 10485760, vtb);
  // wo cast into the dead wq slot
  cast_f32_bf16<<<4096, 256, 0, stream>>>(wo, wob, 1048576);
  // 4) attention
  attn_fwd<<<2048, 256, 0, stream>>>(qb, kb, vtb, ob);
  // 5) output projection
  gemm_bt<<<gq, 256, 0, stream>>>(ob, wob, out, 4096, 2048, 2048);
}

// Round 11
// 438.160 us; speedup vs baseline: 1.5880x; 1.1372x over previous
//
#include <hip/hip_runtime.h>
#include <hip/hip_bf16.h>
#include <stdint.h>

// ---------------------------------------------------------------------------
// GQA fused block. Round 11: GEMM rework — 512-thread / 8-wave 128x128 tile,
// BK=64, XOR-8 swizzled LDS (conflict-free ds_read_b128, same scheme as attn),
// 16 waves/CU at 512-block grids. attn unchanged (158 us, VALU-bound; swapped
// QK^T softmax is the next structural candidate).
// ---------------------------------------------------------------------------

#define B_  2
#define S_  2048
#define D_  2048
#define QH_ 32
#define KVH_ 8
#define HD_ 64

typedef unsigned short u16;
typedef __bf16  bf16x8 __attribute__((ext_vector_type(8)));
typedef float   f32x4  __attribute__((ext_vector_type(4)));
typedef u16     u16x8  __attribute__((ext_vector_type(8)));

__device__ __forceinline__ u16 f2b(float f) {
  unsigned u = __float_as_uint(f);
  u += 0x7fffu + ((u >> 16) & 1u);        // round-to-nearest-even
  return (u16)(u >> 16);
}

// async global -> LDS, 16B per lane. LDS dest = wave-uniform base + lane*16.
__device__ __forceinline__ void gload16(const void* g, void* l) {
  __builtin_amdgcn_global_load_lds(
      (const __attribute__((address_space(1))) void*)(uintptr_t)g,
      (__attribute__((address_space(3))) void*)(uint32_t)(uintptr_t)l,
      16, 0, 0);
}

// swizzled LDS b128 read: logical (row, granule g of 8 u16) in a [*, 64] tile.
// Storage granule = g ^ (row & 7)  (matches pre-swizzled gload16 source).
#define LDS8(buf, row, g) \
  (*reinterpret_cast<const bf16x8*>(&(buf)[(row) * 64 + ((((g) ^ ((row) & 7))) << 3)]))

// ---------------------------------------------------------------------------
__global__ __launch_bounds__(256) void cast_f32_bf16(
    const float* __restrict__ in, u16* __restrict__ out, int n4) {
  int i = blockIdx.x * 256 + threadIdx.x;
  if (i >= n4) return;
  float4 v = *reinterpret_cast<const float4*>(&in[(size_t)i * 4]);
  u16 o0 = f2b(v.x), o1 = f2b(v.y), o2 = f2b(v.z), o3 = f2b(v.w);
  unsigned lo = (unsigned)o0 | ((unsigned)o1 << 16);
  unsigned hi = (unsigned)o2 | ((unsigned)o3 << 16);
  uint2 pk; pk.x = lo; pk.y = hi;
  *reinterpret_cast<uint2*>(&out[(size_t)i * 4]) = pk;
}

// ---------------------------------------------------------------------------
// C(M,N) fp32 = A(M,K)bf16 . B(N,K)bf16^T ; 128x128 tile, BK=64, 8 waves
// (512 thr). Wave (wr=wid>>1, wc=wid&1) owns 32x64; acc[2][4]. LDS rows are
// 128B, XOR-8 swizzled -> conflict-free b128 fragment reads (2-way max).
// XCD-chunked block swizzle (bijective; grid sizes divisible by 8).
__global__ __launch_bounds__(512) void gemm_bt(
    const u16* __restrict__ A, const u16* __restrict__ Bm,
    float* __restrict__ C, int M, int N, int K) {
  __shared__ u16 lA[128 * 64];
  __shared__ u16 lB[128 * 64];
  const int t = threadIdx.x, lane = t & 63, wid = t >> 6;
  const int nwg = gridDim.x * gridDim.y;
  const int flat = blockIdx.y * gridDim.x + blockIdx.x;
  const int swz = (flat & 7) * (nwg >> 3) + (flat >> 3);
  const int m0 = (swz / gridDim.x) * 128, n0 = (swz % gridDim.x) * 128;
  const int wr = wid >> 1, wc = wid & 1;
  f32x4 acc[2][4] = {};
  const int srow = t >> 3;                       // staging row 0..63
  const int sg8 = (((t & 7) ^ (srow & 7)) << 3); // pre-swizzled source granule*8
  const u16* gA = A + (size_t)(m0 + srow) * K + sg8;
  const u16* gB = Bm + (size_t)(n0 + srow) * K + sg8;
  const int rb = lane & 15, hi = lane >> 4;

  for (int k0 = 0; k0 < K; k0 += 64) {
    gload16(gA + k0,                  &lA[wid * 512]);
    gload16(gA + k0 + (size_t)64 * K, &lA[4096 + wid * 512]);
    gload16(gB + k0,                  &lB[wid * 512]);
    gload16(gB + k0 + (size_t)64 * K, &lB[4096 + wid * 512]);
    __syncthreads();
#pragma unroll
    for (int half = 0; half < 2; half++) {
      bf16x8 af[2], bfr[4];
#pragma unroll
      for (int i = 0; i < 2; i++)
        af[i] = LDS8(lA, wr * 32 + i * 16 + rb, half * 4 + hi);
#pragma unroll
      for (int j = 0; j < 4; j++)
        bfr[j] = LDS8(lB, wc * 64 + j * 16 + rb, half * 4 + hi);
#pragma unroll
      for (int i = 0; i < 2; i++)
#pragma unroll
        for (int j = 0; j < 4; j++)
          acc[i][j] = __builtin_amdgcn_mfma_f32_16x16x32_bf16(af[i], bfr[j], acc[i][j], 0, 0, 0);
    }
    __syncthreads();
  }
  const int rg = hi * 4;
#pragma unroll
  for (int i = 0; i < 2; i++)
#pragma unroll
    for (int j = 0; j < 4; j++)
#pragma unroll
      for (int r = 0; r < 4; r++)
        C[(size_t)(m0 + wr * 32 + i * 16 + rg + r) * N + (n0 + wc * 64 + j * 16 + rb)] = acc[i][j][r];
}

// ---------------------------------------------------------------------------
// RMSNorm+RoPE + transpose to (b,H,s,hd). Q: bf16 pre-scaled; K: bf16+fp32.
__global__ __launch_bounds__(256) void postproc(
    const float* __restrict__ lin, const float* __restrict__ freq,
    const float* __restrict__ nw, u16* __restrict__ outb,
    float* __restrict__ outf, int H, float oscale) {
  int p = blockIdx.x * 256 + threadIdx.x;   // pair index
  int i = p & 31;
  int h = (p >> 5) & (H - 1);
  int s = (p / (32 * H)) & (S_ - 1);
  int b = p / (32 * H * S_);
  float2 xv = *reinterpret_cast<const float2*>(
      &lin[(((size_t)b * S_ + s) * H + h) * 64 + 2 * i]);
  float x1 = xv.x, x2 = xv.y;
  float ss = x1 * x1 + x2 * x2;
  ss += __shfl_xor(ss, 1);  ss += __shfl_xor(ss, 2);
  ss += __shfl_xor(ss, 4);  ss += __shfl_xor(ss, 8);
  ss += __shfl_xor(ss, 16);                        // 32-lane group = one row
  float inv = rsqrtf(ss * (1.0f / 64.0f) + 1e-6f);
  x1 *= inv * nw[2 * i];
  x2 *= inv * nw[2 * i + 1];
  float a = freq[(size_t)s * 32 + i];
  float sn, cs;
  __sincosf(a, &sn, &cs);
  float o1 = (x1 * cs - x2 * sn) * oscale;
  float o2 = (x1 * sn + x2 * cs) * oscale;
  size_t oidx = (((size_t)b * H + h) * S_ + s) * 64 + 2 * i;
  unsigned pk = (unsigned)f2b(o1) | ((unsigned)f2b(o2) << 16);
  *reinterpret_cast<unsigned*>(&outb[oidx]) = pk;
  if (outf) {
    float2 o; o.x = o1; o.y = o2;
    *reinterpret_cast<float2*>(&outf[oidx]) = o;
  }
}

// ---------------------------------------------------------------------------
// V: vlin (b,s,kvh,hd) f32 -> vnew (b,kvh,s,hd) f32  AND  vtb (b,kvh,hd,s) bf16
// One block = one (b,kvh, 64-s tile); LDS transpose.
__global__ __launch_bounds__(256) void v_trans(
    const float* __restrict__ vlin, float* __restrict__ vnew,
    u16* __restrict__ vtb) {
  __shared__ u16 tile[64 * 72];     // [hd][s_local], stride 72 u16 (16B-aligned rows)
  const int blk = blockIdx.x;
  const int st = blk & 31, kvh = (blk >> 5) & 7, b = blk >> 8;
  const int t = threadIdx.x;
  const int sl = t >> 2, c0 = (t & 3) * 16;
  const size_t src  = (((size_t)b * S_ + st * 64 + sl) * KVH_ + kvh) * 64 + c0;
  const size_t dstf = (((size_t)(b * KVH_ + kvh) * S_) + st * 64 + sl) * 64 + c0;
#pragma unroll
  for (int i = 0; i < 4; i++) {
    float4 f = *reinterpret_cast<const float4*>(&vlin[src + i * 4]);
    *reinterpret_cast<float4*>(&vnew[dstf + i * 4]) = f;
    tile[(c0 + i * 4 + 0) * 72 + sl] = f2b(f.x);
    tile[(c0 + i * 4 + 1) * 72 + sl] = f2b(f.y);
    tile[(c0 + i * 4 + 2) * 72 + sl] = f2b(f.z);
    tile[(c0 + i * 4 + 3) * 72 + sl] = f2b(f.w);
  }
  __syncthreads();
  const int hd = t >> 2, p0 = (t & 3) * 16;
  const size_t dstt = ((size_t)(b * KVH_ + kvh) * 64 + hd) * S_ + st * 64 + p0;
  uint4 lo = *reinterpret_cast<const uint4*>(&tile[hd * 72 + p0]);
  uint4 hi = *reinterpret_cast<const uint4*>(&tile[hd * 72 + p0 + 8]);
  *reinterpret_cast<uint4*>(&vtb[dstt])     = lo;
  *reinterpret_cast<uint4*>(&vtb[dstt + 8]) = hi;
}

// ---------------------------------------------------------------------------
// Causal GQA flash attention. Block = (b,h,64 q-rows); 4 waves x 16 rows.
// KV tiles of 64, double-buffered; V pre-transposed (b,kvh,hd,s).
// LDS tiles XOR-swizzled at 16B granule. P tile aliased onto dead lQ
// (aq0/aq1 hoisted to VGPRs) -> 40KB LDS -> 4 blocks/CU.
// Softmax in base-2: Q pre-scaled by 0.125*log2(e), exp2f throughout.
__global__ __launch_bounds__(256, 4) void attn_fwd(
    const u16* __restrict__ Qb, const u16* __restrict__ Kb,
    const u16* __restrict__ Vt, u16* __restrict__ Ob) {
  __shared__ u16 lQ[4096];         // Q rows; dead after frag hoist -> reused as P
  __shared__ u16 lK[2][4096];
  __shared__ u16 lV[2][4096];      // V^T tile: [hd][t_local]

  const int t = threadIdx.x, lane = t & 63, wid = t >> 6;
  const int blk = blockIdx.x;
  const int qt = 31 - (blk >> 6);          // longest blocks launch first
  const int bh = blk & 63;
  const int h = bh & 31;
  const int b = bh >> 5;
  const int kvh = h >> 2;
  const int q0 = qt * 64;
  const size_t qbase  = ((size_t)(b * QH_ + h) * S_ + q0) * 64;
  const size_t kbase  = ((size_t)(b * KVH_ + kvh) * S_) * 64;
  const size_t vtbase = ((size_t)(b * KVH_ + kvh) * 64) * S_;

  const int srow = t >> 3;                       // staging row 0..31
  const int sg8 = (((t & 7) ^ (srow & 7)) << 3); // pre-swizzled source granule*8

  {  // stage Q once
    gload16(Qb + qbase + (size_t)srow * 64 + sg8,        &lQ[wid * 512]);
    gload16(Qb + qbase + (size_t)(32 + srow) * 64 + sg8, &lQ[2048 + wid * 512]);
  }
#define STAGE_KV(kdst, vdst, t0)                                              \
  {                                                                           \
    gload16(Kb + kbase + (size_t)((t0) + srow) * 64 + sg8,      &(kdst)[wid * 512]); \
    gload16(Kb + kbase + (size_t)((t0) + 32 + srow) * 64 + sg8, &(kdst)[2048 + wid * 512]); \
    gload16(Vt + vtbase + (size_t)srow * S_ + (t0) + sg8,        &(vdst)[wid * 512]); \
    gload16(Vt + vtbase + (size_t)(32 + srow) * S_ + (t0) + sg8, &(vdst)[2048 + wid * 512]); \
  }
  STAGE_KV(lK[0], lV[0], 0)
  __syncthreads();

  const int rb = lane & 15, hi = lane >> 4;
  // hoisted Q fragments (rows wid*16+rb, k halves 0..31 / 32..63); after the
  // first-use waitcnt these live in VGPRs and lQ's chunk is dead -> P tile.
  const bf16x8 aq0 = LDS8(lQ, wid * 16 + rb, hi);
  const bf16x8 aq1 = LDS8(lQ, wid * 16 + rb, 4 + hi);
  u16* lPw = &lQ[wid * 1024];      // per-wave P tile aliases own Q rows

  f32x4 accO[4] = {};
  float M[4], L[4];
#pragma unroll
  for (int r = 0; r < 4; r++) { M[r] = -1e30f; L[r] = 0.0f; }

  const int nt = qt + 1;
  for (int tt = 0; tt < nt; ++tt) {
    const int cur = tt & 1;
    if (tt + 1 < nt) STAGE_KV(lK[cur ^ 1], lV[cur ^ 1], (tt + 1) * 64)
    const u16* lKc = lK[cur];
    const u16* lVc = lV[cur];

    // S = Q.K^T : 16 rows x 64 cols per wave (S already in log2 units)
    f32x4 sc[4] = {};
#pragma unroll
    for (int nf = 0; nf < 4; nf++) {
      bf16x8 b0 = LDS8(lKc, nf * 16 + rb, hi);
      bf16x8 b1 = LDS8(lKc, nf * 16 + rb, 4 + hi);
      sc[nf] = __builtin_amdgcn_mfma_f32_16x16x32_bf16(aq0, b0, sc[nf], 0, 0, 0);
      sc[nf] = __builtin_amdgcn_mfma_f32_16x16x32_bf16(aq1, b1, sc[nf], 0, 0, 0);
    }
    if (tt == qt) {  // causal mask on diagonal tile
      const int t0 = tt * 64;
#pragma unroll
      for (int nf = 0; nf < 4; nf++) {
        int colg = t0 + nf * 16 + rb;
#pragma unroll
        for (int r = 0; r < 4; r++) {
          int rowg = q0 + wid * 16 + hi * 4 + r;
          if (colg > rowg) sc[nf][r] = -1e30f;
        }
      }
    }
    // online softmax (base-2; row stats across 16 lanes of each group)
    float fac[4];
#pragma unroll
    for (int r = 0; r < 4; r++) {
      float mx = fmaxf(fmaxf(sc[0][r], sc[1][r]), fmaxf(sc[2][r], sc[3][r]));
      mx = fmaxf(mx, __shfl_xor(mx, 1));
      mx = fmaxf(mx, __shfl_xor(mx, 2));
      mx = fmaxf(mx, __shfl_xor(mx, 4));
      mx = fmaxf(mx, __shfl_xor(mx, 8));
      float mn = fmaxf(M[r], mx);
      fac[r] = exp2f(M[r] - mn);
      M[r] = mn;
    }
    float rs[4] = {0.f, 0.f, 0.f, 0.f};
#pragma unroll
    for (int nf = 0; nf < 4; nf++)
#pragma unroll
      for (int r = 0; r < 4; r++) {
        float pv = exp2f(sc[nf][r] - M[r]);
        sc[nf][r] = pv;
        rs[r] += pv;
      }
#pragma unroll
    for (int r = 0; r < 4; r++) {
      float s4 = rs[r];
      s4 += __shfl_xor(s4, 1); s4 += __shfl_xor(s4, 2);
      s4 += __shfl_xor(s4, 4); s4 += __shfl_xor(s4, 8);
      L[r] = L[r] * fac[r] + s4;
      accO[0][r] *= fac[r]; accO[1][r] *= fac[r];
      accO[2][r] *= fac[r]; accO[3][r] *= fac[r];
    }
    // P -> LDS: pack col pairs via shfl, u32 stores, swizzled granule
#pragma unroll
    for (int nf = 0; nf < 4; nf++)
#pragma unroll
      for (int r = 0; r < 4; r++) {
        float own = sc[nf][r];
        float oth = __shfl_xor(own, 1);
        if (!(lane & 1)) {
          int row = hi * 4 + r;
          int col = nf * 16 + rb;          // even
          unsigned pk = (unsigned)f2b(own) | ((unsigned)f2b(oth) << 16);
          *reinterpret_cast<unsigned*>(&lPw[row * 64 + (col ^ ((row & 7) << 3))]) = pk;
        }
      }
    // O += P.V   (A = P rows, B = V^T rows = hd)
#pragma unroll
    for (int ks = 0; ks < 2; ks++) {
      bf16x8 ap = LDS8(lPw, rb, ks * 4 + hi);
#pragma unroll
      for (int nf = 0; nf < 4; nf++) {
        bf16x8 bv = LDS8(lVc, nf * 16 + rb, ks * 4 + hi);
        accO[nf] = __builtin_amdgcn_mfma_f32_16x16x32_bf16(ap, bv, accO[nf], 0, 0, 0);
      }
    }
    __syncthreads();
  }
  // epilogue: paired u32 stores
  float inv[4];
#pragma unroll
  for (int r = 0; r < 4; r++) inv[r] = 1.0f / L[r];
#pragma unroll
  for (int nf = 0; nf < 4; nf++)
#pragma unroll
    for (int r = 0; r < 4; r++) {
      float own = accO[nf][r] * inv[r];
      float oth = __shfl_xor(own, 1);
      if (!(lane & 1)) {
        int rowg = q0 + wid * 16 + hi * 4 + r;
        size_t idx = ((size_t)b * S_ + rowg) * (QH_ * HD_) + h * 64 + nf * 16 + rb;
        unsigned pk = (unsigned)f2b(own) | ((unsigned)f2b(oth) << 16);
        *reinterpret_cast<unsigned*>(&Ob[idx]) = pk;
      }
    }
}

// ---------------------------------------------------------------------------
extern "C" void kernel_launch(void* const* d_in, const int* in_sizes, int n_in,
                              void* d_out, int out_size, void* d_ws, size_t ws_size,
                              hipStream_t stream) {
  const float* x    = (const float*)d_in[0];
  const float* freq = (const float*)d_in[1];
  const float* wq   = (const float*)d_in[2];
  const float* wk   = (const float*)d_in[3];
  const float* wv   = (const float*)d_in[4];
  const float* wo   = (const float*)d_in[5];
  const float* qnw  = (const float*)d_in[6];
  const float* knw  = (const float*)d_in[7];
  float* out = (float*)d_out;

  char* ws = (char*)d_ws;                       // ~100 MB total
  u16*  xb   = (u16*)(ws);                      // 16777216 B
  u16*  wqb  = (u16*)(ws + 16777216);           //  8388608 B (reused for wob)
  u16*  wkb  = (u16*)(ws + 25165824);           //  2097152 B
  u16*  wvb  = (u16*)(ws + 27262976);           //  2097152 B
  float* qlin = (float*)(ws + 29360128);        // 33554432 B (reused for ob)
  float* klin = (float*)(ws + 62914560);        //  8388608 B
  float* vlin = (float*)(ws + 71303168);        //  8388608 B
  u16*  qb   = (u16*)(ws + 79691776);           // 16777216 B
  u16*  kb   = (u16*)(ws + 96468992);           //  4194304 B
  u16*  vtb  = (u16*)(ws + 100663296);          //  4194304 B (V^T bf16)
  u16*  wob = wqb;            // wq-bf16 dead after Q-proj GEMM
  u16*  ob  = (u16*)qlin;     // q_lin dead after postproc Q

  // 1) casts
  cast_f32_bf16<<<8192, 256, 0, stream>>>(x, xb, 2097152);
  cast_f32_bf16<<<4096, 256, 0, stream>>>(wq, wqb, 1048576);
  cast_f32_bf16<<<1024, 256, 0, stream>>>(wk, wkb, 262144);
  cast_f32_bf16<<<1024, 256, 0, stream>>>(wv, wvb, 262144);
  // 2) projections (512-thread 8-wave GEMM)
  dim3 gq(16, 32), gkv(4, 32);
  gemm_bt<<<gq, 512, 0, stream>>>(xb, wqb, qlin, 4096, 2048, 2048);
  gemm_bt<<<gkv, 512, 0, stream>>>(xb, wkb, klin, 4096, 512, 2048);
  gemm_bt<<<gkv, 512, 0, stream>>>(xb, wvb, vlin, 4096, 512, 2048);
  // 3) norm + rope + layout; Q pre-scaled by HD^-1/2 * log2(e) for exp2 softmax
  postproc<<<16384, 256, 0, stream>>>(qlin, freq, qnw, qb, nullptr, QH_, 0.18033688011112042f);
  postproc<<<4096, 256, 0, stream>>>(klin, freq, knw, kb, out + 8388608, KVH_, 1.0f);
  v_trans<<<512, 256, 0, stream>>>(vlin, out + 10485760, vtb);
  // wo cast into the dead wq slot
  cast_f32_bf16<<<4096, 256, 0, stream>>>(wo, wob, 1048576);
  // 4) attention
  attn_fwd<<<2048, 256, 0, stream>>>(qb, kb, vtb, ob);
  // 5) output projection
  gemm_bt<<<gq, 512, 0, stream>>>(ob, wob, out, 4096, 2048, 2048);
}

// Round 15
// 407.027 us; speedup vs baseline: 1.7095x; 1.0765x over previous
//
#include <hip/hip_runtime.h>
#include <hip/hip_bf16.h>
#include <stdint.h>

// ---------------------------------------------------------------------------
// GQA fused block. Round 15: fourth submit of round-12 diff (three infra
// timeouts; byte-identical to keep the A/B vs 438.2 us clean).
// attn DS-pipe trim — (a) per-lane deferred L reduction (16 shfl/tile
// removed), (b) shuffle-free direct u16 P stores with upgraded swizzle key
// SWZK(row)=(row^((row>>3)<<1))&7 (keeps ALL reads and the new P writes
// conflict-free). GEMM shares the macros (audited neutral).
// ---------------------------------------------------------------------------

#define B_  2
#define S_  2048
#define D_  2048
#define QH_ 32
#define KVH_ 8
#define HD_ 64

typedef unsigned short u16;
typedef __bf16  bf16x8 __attribute__((ext_vector_type(8)));
typedef float   f32x4  __attribute__((ext_vector_type(4)));
typedef u16     u16x8  __attribute__((ext_vector_type(8)));

__device__ __forceinline__ u16 f2b(float f) {
  unsigned u = __float_as_uint(f);
  u += 0x7fffu + ((u >> 16) & 1u);        // round-to-nearest-even
  return (u16)(u >> 16);
}

// async global -> LDS, 16B per lane. LDS dest = wave-uniform base + lane*16.
__device__ __forceinline__ void gload16(const void* g, void* l) {
  __builtin_amdgcn_global_load_lds(
      (const __attribute__((address_space(1))) void*)(uintptr_t)g,
      (__attribute__((address_space(3))) void*)(uint32_t)(uintptr_t)l,
      16, 0, 0);
}

// swizzle key: distinguishes rows 16 apart AND rows 8 apart (stride-128B rows
// land on identical banks, so the key must differ for rows {r,4+r,8+r,12+r}).
#define SWZK(row) ((((row) ^ (((row) >> 3) << 1))) & 7)

// swizzled LDS b128 read: logical (row, granule g of 8 u16) in a [*, 64] tile.
// Storage granule = g ^ SWZK(row)  (matches pre-swizzled gload16 source).
#define LDS8(buf, row, g) \
  (*reinterpret_cast<const bf16x8*>(&(buf)[(row) * 64 + (((g) ^ SWZK(row)) << 3)]))

// ---------------------------------------------------------------------------
__global__ __launch_bounds__(256) void cast_f32_bf16(
    const float* __restrict__ in, u16* __restrict__ out, int n4) {
  int i = blockIdx.x * 256 + threadIdx.x;
  if (i >= n4) return;
  float4 v = *reinterpret_cast<const float4*>(&in[(size_t)i * 4]);
  u16 o0 = f2b(v.x), o1 = f2b(v.y), o2 = f2b(v.z), o3 = f2b(v.w);
  unsigned lo = (unsigned)o0 | ((unsigned)o1 << 16);
  unsigned hi = (unsigned)o2 | ((unsigned)o3 << 16);
  uint2 pk; pk.x = lo; pk.y = hi;
  *reinterpret_cast<uint2*>(&out[(size_t)i * 4]) = pk;
}

// ---------------------------------------------------------------------------
// C(M,N) fp32 = A(M,K)bf16 . B(N,K)bf16^T ; 128x128 tile, BK=64, 8 waves
// (512 thr). Wave (wr=wid>>1, wc=wid&1) owns 32x64; acc[2][4]. LDS rows are
// 128B, XOR-swizzled (SWZK) -> conflict-free b128 fragment reads.
// XCD-chunked block swizzle (bijective; grid sizes divisible by 8).
__global__ __launch_bounds__(512) void gemm_bt(
    const u16* __restrict__ A, const u16* __restrict__ Bm,
    float* __restrict__ C, int M, int N, int K) {
  __shared__ u16 lA[128 * 64];
  __shared__ u16 lB[128 * 64];
  const int t = threadIdx.x, lane = t & 63, wid = t >> 6;
  const int nwg = gridDim.x * gridDim.y;
  const int flat = blockIdx.y * gridDim.x + blockIdx.x;
  const int swz = (flat & 7) * (nwg >> 3) + (flat >> 3);
  const int m0 = (swz / gridDim.x) * 128, n0 = (swz % gridDim.x) * 128;
  const int wr = wid >> 1, wc = wid & 1;
  f32x4 acc[2][4] = {};
  const int srow = t >> 3;                       // staging row 0..63
  const int sg8 = (((t & 7) ^ SWZK(srow)) << 3); // pre-swizzled source granule*8
  const u16* gA = A + (size_t)(m0 + srow) * K + sg8;
  const u16* gB = Bm + (size_t)(n0 + srow) * K + sg8;
  const int rb = lane & 15, hi = lane >> 4;

  for (int k0 = 0; k0 < K; k0 += 64) {
    gload16(gA + k0,                  &lA[wid * 512]);
    gload16(gA + k0 + (size_t)64 * K, &lA[4096 + wid * 512]);
    gload16(gB + k0,                  &lB[wid * 512]);
    gload16(gB + k0 + (size_t)64 * K, &lB[4096 + wid * 512]);
    __syncthreads();
#pragma unroll
    for (int half = 0; half < 2; half++) {
      bf16x8 af[2], bfr[4];
#pragma unroll
      for (int i = 0; i < 2; i++)
        af[i] = LDS8(lA, wr * 32 + i * 16 + rb, half * 4 + hi);
#pragma unroll
      for (int j = 0; j < 4; j++)
        bfr[j] = LDS8(lB, wc * 64 + j * 16 + rb, half * 4 + hi);
#pragma unroll
      for (int i = 0; i < 2; i++)
#pragma unroll
        for (int j = 0; j < 4; j++)
          acc[i][j] = __builtin_amdgcn_mfma_f32_16x16x32_bf16(af[i], bfr[j], acc[i][j], 0, 0, 0);
    }
    __syncthreads();
  }
  const int rg = hi * 4;
#pragma unroll
  for (int i = 0; i < 2; i++)
#pragma unroll
    for (int j = 0; j < 4; j++)
#pragma unroll
      for (int r = 0; r < 4; r++)
        C[(size_t)(m0 + wr * 32 + i * 16 + rg + r) * N + (n0 + wc * 64 + j * 16 + rb)] = acc[i][j][r];
}

// ---------------------------------------------------------------------------
// RMSNorm+RoPE + transpose to (b,H,s,hd). Q: bf16 pre-scaled; K: bf16+fp32.
__global__ __launch_bounds__(256) void postproc(
    const float* __restrict__ lin, const float* __restrict__ freq,
    const float* __restrict__ nw, u16* __restrict__ outb,
    float* __restrict__ outf, int H, float oscale) {
  int p = blockIdx.x * 256 + threadIdx.x;   // pair index
  int i = p & 31;
  int h = (p >> 5) & (H - 1);
  int s = (p / (32 * H)) & (S_ - 1);
  int b = p / (32 * H * S_);
  float2 xv = *reinterpret_cast<const float2*>(
      &lin[(((size_t)b * S_ + s) * H + h) * 64 + 2 * i]);
  float x1 = xv.x, x2 = xv.y;
  float ss = x1 * x1 + x2 * x2;
  ss += __shfl_xor(ss, 1);  ss += __shfl_xor(ss, 2);
  ss += __shfl_xor(ss, 4);  ss += __shfl_xor(ss, 8);
  ss += __shfl_xor(ss, 16);                        // 32-lane group = one row
  float inv = rsqrtf(ss * (1.0f / 64.0f) + 1e-6f);
  x1 *= inv * nw[2 * i];
  x2 *= inv * nw[2 * i + 1];
  float a = freq[(size_t)s * 32 + i];
  float sn, cs;
  __sincosf(a, &sn, &cs);
  float o1 = (x1 * cs - x2 * sn) * oscale;
  float o2 = (x1 * sn + x2 * cs) * oscale;
  size_t oidx = (((size_t)b * H + h) * S_ + s) * 64 + 2 * i;
  unsigned pk = (unsigned)f2b(o1) | ((unsigned)f2b(o2) << 16);
  *reinterpret_cast<unsigned*>(&outb[oidx]) = pk;
  if (outf) {
    float2 o; o.x = o1; o.y = o2;
    *reinterpret_cast<float2*>(&outf[oidx]) = o;
  }
}

// ---------------------------------------------------------------------------
// V: vlin (b,s,kvh,hd) f32 -> vnew (b,kvh,s,hd) f32  AND  vtb (b,kvh,hd,s) bf16
// One block = one (b,kvh, 64-s tile); LDS transpose.
__global__ __launch_bounds__(256) void v_trans(
    const float* __restrict__ vlin, float* __restrict__ vnew,
    u16* __restrict__ vtb) {
  __shared__ u16 tile[64 * 72];     // [hd][s_local], stride 72 u16 (16B-aligned rows)
  const int blk = blockIdx.x;
  const int st = blk & 31, kvh = (blk >> 5) & 7, b = blk >> 8;
  const int t = threadIdx.x;
  const int sl = t >> 2, c0 = (t & 3) * 16;
  const size_t src  = (((size_t)b * S_ + st * 64 + sl) * KVH_ + kvh) * 64 + c0;
  const size_t dstf = (((size_t)(b * KVH_ + kvh) * S_) + st * 64 + sl) * 64 + c0;
#pragma unroll
  for (int i = 0; i < 4; i++) {
    float4 f = *reinterpret_cast<const float4*>(&vlin[src + i * 4]);
    *reinterpret_cast<float4*>(&vnew[dstf + i * 4]) = f;
    tile[(c0 + i * 4 + 0) * 72 + sl] = f2b(f.x);
    tile[(c0 + i * 4 + 1) * 72 + sl] = f2b(f.y);
    tile[(c0 + i * 4 + 2) * 72 + sl] = f2b(f.z);
    tile[(c0 + i * 4 + 3) * 72 + sl] = f2b(f.w);
  }
  __syncthreads();
  const int hd = t >> 2, p0 = (t & 3) * 16;
  const size_t dstt = ((size_t)(b * KVH_ + kvh) * 64 + hd) * S_ + st * 64 + p0;
  uint4 lo = *reinterpret_cast<const uint4*>(&tile[hd * 72 + p0]);
  uint4 hi = *reinterpret_cast<const uint4*>(&tile[hd * 72 + p0 + 8]);
  *reinterpret_cast<uint4*>(&vtb[dstt])     = lo;
  *reinterpret_cast<uint4*>(&vtb[dstt + 8]) = hi;
}

// ---------------------------------------------------------------------------
// Causal GQA flash attention. Block = (b,h,64 q-rows); 4 waves x 16 rows.
// KV tiles of 64, double-buffered; V pre-transposed (b,kvh,hd,s).
// LDS tiles XOR-swizzled (SWZK). P tile aliased onto dead lQ -> 40KB LDS.
// Per-lane deferred L; shuffle-free direct u16 P stores (conflict-free).
// Softmax in base-2: Q pre-scaled by 0.125*log2(e), exp2f throughout.
__global__ __launch_bounds__(256, 4) void attn_fwd(
    const u16* __restrict__ Qb, const u16* __restrict__ Kb,
    const u16* __restrict__ Vt, u16* __restrict__ Ob) {
  __shared__ u16 lQ[4096];         // Q rows; dead after frag hoist -> reused as P
  __shared__ u16 lK[2][4096];
  __shared__ u16 lV[2][4096];      // V^T tile: [hd][t_local]

  const int t = threadIdx.x, lane = t & 63, wid = t >> 6;
  const int blk = blockIdx.x;
  const int qt = 31 - (blk >> 6);          // longest blocks launch first
  const int bh = blk & 63;
  const int h = bh & 31;
  const int b = bh >> 5;
  const int kvh = h >> 2;
  const int q0 = qt * 64;
  const size_t qbase  = ((size_t)(b * QH_ + h) * S_ + q0) * 64;
  const size_t kbase  = ((size_t)(b * KVH_ + kvh) * S_) * 64;
  const size_t vtbase = ((size_t)(b * KVH_ + kvh) * 64) * S_;

  const int srow = t >> 3;                       // staging row 0..31
  const int sg8 = (((t & 7) ^ SWZK(srow)) << 3); // pre-swizzled source granule*8

  {  // stage Q once
    gload16(Qb + qbase + (size_t)srow * 64 + sg8,        &lQ[wid * 512]);
    gload16(Qb + qbase + (size_t)(32 + srow) * 64 + sg8, &lQ[2048 + wid * 512]);
  }
#define STAGE_KV(kdst, vdst, t0)                                              \
  {                                                                           \
    gload16(Kb + kbase + (size_t)((t0) + srow) * 64 + sg8,      &(kdst)[wid * 512]); \
    gload16(Kb + kbase + (size_t)((t0) + 32 + srow) * 64 + sg8, &(kdst)[2048 + wid * 512]); \
    gload16(Vt + vtbase + (size_t)srow * S_ + (t0) + sg8,        &(vdst)[wid * 512]); \
    gload16(Vt + vtbase + (size_t)(32 + srow) * S_ + (t0) + sg8, &(vdst)[2048 + wid * 512]); \
  }
  STAGE_KV(lK[0], lV[0], 0)
  __syncthreads();

  const int rb = lane & 15, hi = lane >> 4;
  // hoisted Q fragments; after the first-use waitcnt these live in VGPRs and
  // lQ's chunk is dead -> per-wave P tile.
  const bf16x8 aq0 = LDS8(lQ, wid * 16 + rb, hi);
  const bf16x8 aq1 = LDS8(lQ, wid * 16 + rb, 4 + hi);
  u16* lPw = &lQ[wid * 1024];      // per-wave P tile aliases own Q rows

  f32x4 accO[4] = {};
  float M[4], Lp[4];               // Lp = per-lane partial denominator
#pragma unroll
  for (int r = 0; r < 4; r++) { M[r] = -1e30f; Lp[r] = 0.0f; }

  const int nt = qt + 1;
  for (int tt = 0; tt < nt; ++tt) {
    const int cur = tt & 1;
    if (tt + 1 < nt) STAGE_KV(lK[cur ^ 1], lV[cur ^ 1], (tt + 1) * 64)
    const u16* lKc = lK[cur];
    const u16* lVc = lV[cur];

    // S = Q.K^T : 16 rows x 64 cols per wave (S already in log2 units)
    f32x4 sc[4] = {};
#pragma unroll
    for (int nf = 0; nf < 4; nf++) {
      bf16x8 b0 = LDS8(lKc, nf * 16 + rb, hi);
      bf16x8 b1 = LDS8(lKc, nf * 16 + rb, 4 + hi);
      sc[nf] = __builtin_amdgcn_mfma_f32_16x16x32_bf16(aq0, b0, sc[nf], 0, 0, 0);
      sc[nf] = __builtin_amdgcn_mfma_f32_16x16x32_bf16(aq1, b1, sc[nf], 0, 0, 0);
    }
    if (tt == qt) {  // causal mask on diagonal tile
      const int t0 = tt * 64;
#pragma unroll
      for (int nf = 0; nf < 4; nf++) {
        int colg = t0 + nf * 16 + rb;
#pragma unroll
        for (int r = 0; r < 4; r++) {
          int rowg = q0 + wid * 16 + hi * 4 + r;
          if (colg > rowg) sc[nf][r] = -1e30f;
        }
      }
    }
    // online softmax (base-2; row max across 16 lanes of each group)
    float fac[4];
#pragma unroll
    for (int r = 0; r < 4; r++) {
      float mx = fmaxf(fmaxf(sc[0][r], sc[1][r]), fmaxf(sc[2][r], sc[3][r]));
      mx = fmaxf(mx, __shfl_xor(mx, 1));
      mx = fmaxf(mx, __shfl_xor(mx, 2));
      mx = fmaxf(mx, __shfl_xor(mx, 4));
      mx = fmaxf(mx, __shfl_xor(mx, 8));
      float mn = fmaxf(M[r], mx);
      fac[r] = exp2f(M[r] - mn);
      M[r] = mn;
    }
#pragma unroll
    for (int r = 0; r < 4; r++) {
      float rs = 0.f;
#pragma unroll
      for (int nf = 0; nf < 4; nf++) {
        float pv = exp2f(sc[nf][r] - M[r]);
        sc[nf][r] = pv;
        rs += pv;
      }
      Lp[r] = Lp[r] * fac[r] + rs;           // per-lane partial; reduce at end
      accO[0][r] *= fac[r]; accO[1][r] *= fac[r];
      accO[2][r] *= fac[r]; accO[3][r] *= fac[r];
    }
    // P -> LDS: direct u16 stores, all lanes, SWZK granule (conflict-free)
#pragma unroll
    for (int nf = 0; nf < 4; nf++) {
      const int cg = nf * 2 + (rb >> 3), co = rb & 7;
#pragma unroll
      for (int r = 0; r < 4; r++) {
        int row = hi * 4 + r;
        lPw[row * 64 + ((cg ^ SWZK(row)) << 3) + co] = f2b(sc[nf][r]);
      }
    }
    // O += P.V   (A = P rows, B = V^T rows = hd)
#pragma unroll
    for (int ks = 0; ks < 2; ks++) {
      bf16x8 ap = LDS8(lPw, rb, ks * 4 + hi);
#pragma unroll
      for (int nf = 0; nf < 4; nf++) {
        bf16x8 bv = LDS8(lVc, nf * 16 + rb, ks * 4 + hi);
        accO[nf] = __builtin_amdgcn_mfma_f32_16x16x32_bf16(ap, bv, accO[nf], 0, 0, 0);
      }
    }
    __syncthreads();
  }
  // epilogue: reduce Lp across the 16-lane row group, then paired u32 stores
  float inv[4];
#pragma unroll
  for (int r = 0; r < 4; r++) {
    float Ls = Lp[r];
    Ls += __shfl_xor(Ls, 1); Ls += __shfl_xor(Ls, 2);
    Ls += __shfl_xor(Ls, 4); Ls += __shfl_xor(Ls, 8);
    inv[r] = 1.0f / Ls;
  }
#pragma unroll
  for (int nf = 0; nf < 4; nf++)
#pragma unroll
    for (int r = 0; r < 4; r++) {
      float own = accO[nf][r] * inv[r];
      float oth = __shfl_xor(own, 1);
      if (!(lane & 1)) {
        int rowg = q0 + wid * 16 + hi * 4 + r;
        size_t idx = ((size_t)b * S_ + rowg) * (QH_ * HD_) + h * 64 + nf * 16 + rb;
        unsigned pk = (unsigned)f2b(own) | ((unsigned)f2b(oth) << 16);
        *reinterpret_cast<unsigned*>(&Ob[idx]) = pk;
      }
    }
}

// ---------------------------------------------------------------------------
extern "C" void kernel_launch(void* const* d_in, const int* in_sizes, int n_in,
                              void* d_out, int out_size, void* d_ws, size_t ws_size,
                              hipStream_t stream) {
  const float* x    = (const float*)d_in[0];
  const float* freq = (const float*)d_in[1];
  const float* wq   = (const float*)d_in[2];
  const float* wk   = (const float*)d_in[3];
  const float* wv   = (const float*)d_in[4];
  const float* wo   = (const float*)d_in[5];
  const float* qnw  = (const float*)d_in[6];
  const float* knw  = (const float*)d_in[7];
  float* out = (float*)d_out;

  char* ws = (char*)d_ws;                       // ~100 MB total
  u16*  xb   = (u16*)(ws);                      // 16777216 B
  u16*  wqb  = (u16*)(ws + 16777216);           //  8388608 B (reused for wob)
  u16*  wkb  = (u16*)(ws + 25165824);           //  2097152 B
  u16*  wvb  = (u16*)(ws + 27262976);           //  2097152 B
  float* qlin = (float*)(ws + 29360128);        // 33554432 B (reused for ob)
  float* klin = (float*)(ws + 62914560);        //  8388608 B
  float* vlin = (float*)(ws + 71303168);        //  8388608 B
  u16*  qb   = (u16*)(ws + 79691776);           // 16777216 B
  u16*  kb   = (u16*)(ws + 96468992);           //  4194304 B
  u16*  vtb  = (u16*)(ws + 100663296);          //  4194304 B (V^T bf16)
  u16*  wob = wqb;            // wq-bf16 dead after Q-proj GEMM
  u16*  ob  = (u16*)qlin;     // q_lin dead after postproc Q

  // 1) casts
  cast_f32_bf16<<<8192, 256, 0, stream>>>(x, xb, 2097152);
  cast_f32_bf16<<<4096, 256, 0, stream>>>(wq, wqb, 1048576);
  cast_f32_bf16<<<1024, 256, 0, stream>>>(wk, wkb, 262144);
  cast_f32_bf16<<<1024, 256, 0, stream>>>(wv, wvb, 262144);
  // 2) projections (512-thread 8-wave GEMM)
  dim3 gq(16, 32), gkv(4, 32);
  gemm_bt<<<gq, 512, 0, stream>>>(xb, wqb, qlin, 4096, 2048, 2048);
  gemm_bt<<<gkv, 512, 0, stream>>>(xb, wkb, klin, 4096, 512, 2048);
  gemm_bt<<<gkv, 512, 0, stream>>>(xb, wvb, vlin, 4096, 512, 2048);
  // 3) norm + rope + layout; Q pre-scaled by HD^-1/2 * log2(e) for exp2 softmax
  postproc<<<16384, 256, 0, stream>>>(qlin, freq, qnw, qb, nullptr, QH_, 0.18033688011112042f);
  postproc<<<4096, 256, 0, stream>>>(klin, freq, knw, kb, out + 8388608, KVH_, 1.0f);
  v_trans<<<512, 256, 0, stream>>>(vlin, out + 10485760, vtb);
  // wo cast into the dead wq slot
  cast_f32_bf16<<<4096, 256, 0, stream>>>(wo, wob, 1048576);
  // 4) attention
  attn_fwd<<<2048, 256, 0, stream>>>(qb, kb, vtb, ob);
  // 5) output projection
  gemm_bt<<<gq, 512, 0, stream>>>(ob, wob, out, 4096, 2048, 2048);
}